// Round 1
// baseline (1747.488 us; speedup 1.0000x reference)
//
#include <hip/hip_runtime.h>

typedef __attribute__((ext_vector_type(8))) short short8;
typedef __attribute__((ext_vector_type(4))) float f32x4;
typedef unsigned short u16;
typedef unsigned int u32;

// round-to-nearest-even f32 -> bf16
__device__ __forceinline__ u16 f2bf(float f){
  union { float f; u32 u; } v; v.f = f;
  u32 u = v.u;
  u32 r = (u + 0x7FFFu + ((u >> 16) & 1u)) >> 16;
  return (u16)r;
}

// XOR swizzle on byte-in-row (bits 4..6) to break power-of-2 row strides
__device__ __forceinline__ int swz(int row, int cb){ return cb ^ ((row & 7) << 4); }

// ---------------------------------------------------------------------------
// Weight pre-transpose + bf16 convert:  wqkvt[e][k] = bf16(w_qkv[k][e]),
//                                       wprojt[c][f] = bf16(w_proj[f][c])
// ---------------------------------------------------------------------------
__global__ void convert_weights(const float* __restrict__ wqkv,
                                const float* __restrict__ wproj,
                                u16* __restrict__ wqkvt,
                                u16* __restrict__ wprojt){
  int tid = blockIdx.x * 256 + threadIdx.x;
  union { u16 u[8]; uint4 v; } tmp;
  if (tid < 1536 * 64){
    int e  = tid >> 6;
    int kc = (tid & 63) << 3;
    #pragma unroll
    for (int i = 0; i < 8; ++i) tmp.u[i] = f2bf(wqkv[(long)(kc + i) * 1536 + e]);
    *reinterpret_cast<uint4*>(wqkvt + (long)e * 512 + kc) = tmp.v;
  } else {
    int t2 = tid - 1536 * 64;
    int c  = t2 >> 6;
    int kc = (t2 & 63) << 3;
    #pragma unroll
    for (int i = 0; i < 8; ++i) tmp.u[i] = f2bf(wproj[(long)(kc + i) * 512 + c]);
    *reinterpret_cast<uint4*>(wprojt + (long)c * 512 + kc) = tmp.v;
  }
}

// ---------------------------------------------------------------------------
// Fused window attention: one block = one 64-token window, 8 waves.
//   Phase A: QKV_h = Xw(64x512) @ Wqkv_h(512x192)      (per head h)
//   Phase B: S = Q K^T * 0.125, softmax -> P           (waves 0..3)
//   Phase C: O_h = P @ V
//   Phase D: out_acc += O_h @ Wproj[h*64:(h+1)*64, :]  (regs, 16 frags/wave)
// ---------------------------------------------------------------------------
__global__ __launch_bounds__(512, 2) void fused_winattn(
    const float* __restrict__ x,
    const u16*  __restrict__ wqkvt,
    const float* __restrict__ bqkv,
    const u16*  __restrict__ wprojt,
    const float* __restrict__ bproj,
    float* __restrict__ out)
{
  __shared__ u16 lds_x[64 * 512];   // 64 KB, row stride 1024 B, swizzled
  __shared__ u16 lds_q[64 * 64];    // 8 KB  [tok][d]   (reused as O_h buffer)
  __shared__ u16 lds_k[64 * 64];    // 8 KB  [tok][d]
  __shared__ u16 lds_vt[64 * 64];   // 8 KB  [d][tok]
  __shared__ u16 lds_p[64 * 64];    // 8 KB  [i][j]

  const int tid = threadIdx.x;
  const int l   = tid & 63;
  const int w   = tid >> 6;        // wave id 0..7
  const int g   = l >> 4;          // k-chunk group 0..3
  const int ln  = l & 15;
  const long tokbase = (long)blockIdx.x * 64;

  // ---- stage x window -> bf16 LDS (coalesced float4 loads) ----
  {
    const float4* xv = reinterpret_cast<const float4*>(x + tokbase * 512);
    #pragma unroll
    for (int j = 0; j < 16; ++j){
      int i   = j * 512 + tid;         // float4 index in 64x128
      int row = i >> 7;
      int c4  = i & 127;
      float4 v = xv[i];
      uint2 pk;
      pk.x = (u32)f2bf(v.x) | ((u32)f2bf(v.y) << 16);
      pk.y = (u32)f2bf(v.z) | ((u32)f2bf(v.w) << 16);
      int byte = row * 1024 + swz(row, c4 * 8);
      *reinterpret_cast<uint2*>(reinterpret_cast<char*>(lds_x) + byte) = pk;
    }
  }

  f32x4 oacc[4][4];
  #pragma unroll
  for (int m = 0; m < 4; ++m)
    #pragma unroll
    for (int n = 0; n < 4; ++n) oacc[m][n] = (f32x4){0.f, 0.f, 0.f, 0.f};

  const int mw   = w & 3;
  const int half = w >> 2;

  __syncthreads();

  for (int h = 0; h < 8; ++h){
    // ================= Phase A: QKV GEMM =================
    // wave w computes m-tile mw for n-tiles [half*6 .. half*6+5] of the
    // 64x192 output (Q: nt 0-3, K: nt 4-7, V: nt 8-11)
    f32x4 qacc[6];
    #pragma unroll
    for (int j = 0; j < 6; ++j) qacc[j] = (f32x4){0.f, 0.f, 0.f, 0.f};
    int ebase[6];
    #pragma unroll
    for (int j = 0; j < 6; ++j){
      int nt = half * 6 + j;
      int sec = nt >> 2;                       // 0=Q 1=K 2=V
      ebase[j] = sec * 512 + h * 64 + (nt & 3) * 16;
    }
    const int arow = mw * 16 + ln;
    #pragma unroll
    for (int ks = 0; ks < 16; ++ks){
      short8 a = *reinterpret_cast<const short8*>(
          reinterpret_cast<const char*>(lds_x) + arow * 1024 + swz(arow, (ks * 32 + g * 8) * 2));
      #pragma unroll
      for (int j = 0; j < 6; ++j){
        short8 b = *reinterpret_cast<const short8*>(
            wqkvt + (long)(ebase[j] + ln) * 512 + ks * 32 + g * 8);
        qacc[j] = __builtin_amdgcn_mfma_f32_16x16x32_bf16(a, b, qacc[j], 0, 0, 0);
      }
    }
    // write Q,K (row-major [tok][d]) and V (transposed [d][tok]) to LDS
    #pragma unroll
    for (int j = 0; j < 6; ++j){
      int nt  = half * 6 + j;
      int sec = nt >> 2;
      float bias = bqkv[ebase[j] + ln];
      if (sec < 2){
        u16* dst = (sec == 0) ? lds_q : lds_k;
        int c = (nt & 3) * 16 + ln;
        #pragma unroll
        for (int r = 0; r < 4; ++r){
          int t = mw * 16 + g * 4 + r;
          int byte = t * 128 + swz(t, c * 2);
          *reinterpret_cast<u16*>(reinterpret_cast<char*>(dst) + byte) = f2bf(qacc[j][r] + bias);
        }
      } else {
        int d  = (nt & 3) * 16 + ln;
        int t0 = mw * 16 + g * 4;
        uint2 pk;
        pk.x = (u32)f2bf(qacc[j][0] + bias) | ((u32)f2bf(qacc[j][1] + bias) << 16);
        pk.y = (u32)f2bf(qacc[j][2] + bias) | ((u32)f2bf(qacc[j][3] + bias) << 16);
        int byte = d * 128 + swz(d, t0 * 2);
        *reinterpret_cast<uint2*>(reinterpret_cast<char*>(lds_vt) + byte) = pk;
      }
    }
    __syncthreads();

    // ================= Phase B: scores + softmax (waves 0..3) =================
    if (w < 4){
      f32x4 sacc[4];
      #pragma unroll
      for (int jt = 0; jt < 4; ++jt) sacc[jt] = (f32x4){0.f, 0.f, 0.f, 0.f};
      #pragma unroll
      for (int ks = 0; ks < 2; ++ks){
        int qrow = w * 16 + ln;
        short8 a = *reinterpret_cast<const short8*>(
            reinterpret_cast<const char*>(lds_q) + qrow * 128 + swz(qrow, (ks * 32 + g * 8) * 2));
        #pragma unroll
        for (int jt = 0; jt < 4; ++jt){
          int krow = jt * 16 + ln;
          short8 b = *reinterpret_cast<const short8*>(
              reinterpret_cast<const char*>(lds_k) + krow * 128 + swz(krow, (ks * 32 + g * 8) * 2));
          sacc[jt] = __builtin_amdgcn_mfma_f32_16x16x32_bf16(a, b, sacc[jt], 0, 0, 0);
        }
      }
      // per-row softmax: row i held by the 16 lanes of group g (one col/frag each)
      #pragma unroll
      for (int r = 0; r < 4; ++r){
        float mx = fmaxf(fmaxf(sacc[0][r], sacc[1][r]), fmaxf(sacc[2][r], sacc[3][r]));
        mx = fmaxf(mx, __shfl_xor(mx, 1, 64));
        mx = fmaxf(mx, __shfl_xor(mx, 2, 64));
        mx = fmaxf(mx, __shfl_xor(mx, 4, 64));
        mx = fmaxf(mx, __shfl_xor(mx, 8, 64));
        float p[4], s = 0.f;
        #pragma unroll
        for (int jt = 0; jt < 4; ++jt){
          p[jt] = __expf((sacc[jt][r] - mx) * 0.125f);
          s += p[jt];
        }
        s += __shfl_xor(s, 1, 64);
        s += __shfl_xor(s, 2, 64);
        s += __shfl_xor(s, 4, 64);
        s += __shfl_xor(s, 8, 64);
        float inv = 1.f / s;
        int i = w * 16 + g * 4 + r;
        #pragma unroll
        for (int jt = 0; jt < 4; ++jt){
          int c = jt * 16 + ln;
          int byte = i * 128 + swz(i, c * 2);
          *reinterpret_cast<u16*>(reinterpret_cast<char*>(lds_p) + byte) = f2bf(p[jt] * inv);
        }
      }
    }
    __syncthreads();

    // ================= Phase C: O = P @ V =================
    {
      int mc  = w & 3;
      int nc0 = (w >> 2) * 2;
      f32x4 oc[2];
      oc[0] = (f32x4){0.f, 0.f, 0.f, 0.f};
      oc[1] = (f32x4){0.f, 0.f, 0.f, 0.f};
      #pragma unroll
      for (int ks = 0; ks < 2; ++ks){
        int prow = mc * 16 + ln;
        short8 a = *reinterpret_cast<const short8*>(
            reinterpret_cast<const char*>(lds_p) + prow * 128 + swz(prow, (ks * 32 + g * 8) * 2));
        #pragma unroll
        for (int jj = 0; jj < 2; ++jj){
          int vrow = (nc0 + jj) * 16 + ln;
          short8 b = *reinterpret_cast<const short8*>(
              reinterpret_cast<const char*>(lds_vt) + vrow * 128 + swz(vrow, (ks * 32 + g * 8) * 2));
          oc[jj] = __builtin_amdgcn_mfma_f32_16x16x32_bf16(a, b, oc[jj], 0, 0, 0);
        }
      }
      // write O_h into lds_q (row-major [tok][d]); lds_q is dead after phase B
      #pragma unroll
      for (int jj = 0; jj < 2; ++jj){
        int d = (nc0 + jj) * 16 + ln;
        #pragma unroll
        for (int r = 0; r < 4; ++r){
          int t = mc * 16 + g * 4 + r;
          int byte = t * 128 + swz(t, d * 2);
          *reinterpret_cast<u16*>(reinterpret_cast<char*>(lds_q) + byte) = f2bf(oc[jj][r]);
        }
      }
    }
    __syncthreads();

    // ================= Phase D: out_acc += O_h @ Wp_h =================
    // wave w owns out cols [w*64, w*64+64), all 4 m-tiles (16 frags in regs)
    #pragma unroll
    for (int ks = 0; ks < 2; ++ks){
      short8 a[4];
      #pragma unroll
      for (int m = 0; m < 4; ++m){
        int row = m * 16 + ln;
        a[m] = *reinterpret_cast<const short8*>(
            reinterpret_cast<const char*>(lds_q) + row * 128 + swz(row, (ks * 32 + g * 8) * 2));
      }
      #pragma unroll
      for (int nt = 0; nt < 4; ++nt){
        int e = w * 64 + nt * 16 + ln;
        short8 b = *reinterpret_cast<const short8*>(
            wprojt + (long)e * 512 + h * 64 + ks * 32 + g * 8);
        #pragma unroll
        for (int m = 0; m < 4; ++m)
          oacc[m][nt] = __builtin_amdgcn_mfma_f32_16x16x32_bf16(a[m], b, oacc[m][nt], 0, 0, 0);
      }
    }
    __syncthreads();
  }

  // ================= epilogue: bias + f32 store =================
  #pragma unroll
  for (int nt = 0; nt < 4; ++nt){
    int col = w * 64 + nt * 16 + ln;
    float bias = bproj[col];
    #pragma unroll
    for (int m = 0; m < 4; ++m){
      #pragma unroll
      for (int r = 0; r < 4; ++r){
        int t = m * 16 + g * 4 + r;
        out[(tokbase + t) * 512 + col] = oacc[m][nt][r] + bias;
      }
    }
  }
}

extern "C" void kernel_launch(void* const* d_in, const int* in_sizes, int n_in,
                              void* d_out, int out_size, void* d_ws, size_t ws_size,
                              hipStream_t stream) {
  const float* x     = (const float*)d_in[0];
  const float* wqkv  = (const float*)d_in[1];
  const float* bqkv  = (const float*)d_in[2];
  const float* wproj = (const float*)d_in[3];
  const float* bproj = (const float*)d_in[4];
  float* out = (float*)d_out;

  u16* wqkvt  = (u16*)d_ws;                 // 1536 x 512 bf16 (1.5 MB)
  u16* wprojt = wqkvt + 1536 * 512;         //  512 x 512 bf16 (0.5 MB)

  convert_weights<<<512, 256, 0, stream>>>(wqkv, wproj, wqkvt, wprojt);
  fused_winattn<<<2048, 512, 0, stream>>>(x, wqkvt, bqkv, wprojt, bproj, out);
}

// Round 2
// 913.388 us; speedup vs baseline: 1.9132x; 1.9132x over previous
//
#include <hip/hip_runtime.h>

typedef __attribute__((ext_vector_type(8))) short short8;
typedef __attribute__((ext_vector_type(4))) float f32x4;
typedef unsigned short u16;
typedef unsigned int u32;

// round-to-nearest-even f32 -> bf16
__device__ __forceinline__ u16 f2bf(float f){
  union { float f; u32 u; } v; v.f = f;
  u32 u = v.u;
  u32 r = (u + 0x7FFFu + ((u >> 16) & 1u)) >> 16;
  return (u16)r;
}

// XOR swizzle on byte-in-row (bits 4..6) to break power-of-2 row strides
__device__ __forceinline__ int swz(int row, int cb){ return cb ^ ((row & 7) << 4); }

// async global->LDS 16B copy (wave-uniform LDS base, lane-strided dest)
__device__ __forceinline__ void gload16(const void* g, void* l){
  __builtin_amdgcn_global_load_lds(
      (const __attribute__((address_space(1))) unsigned int*)g,
      (__attribute__((address_space(3))) unsigned int*)l, 16, 0, 0);
}

// ===========================================================================
// K0: weight convert + transpose + tile-block + pre-swizzle.
// Layout per 128x64 tile (16 KB): chunk (row, c7) 16B holds logical
// B[row][ (c7 ^ (row&7))*8 .. +8 ) so that LINEAR global_load_lds yields a
// swizzled LDS image read conflict-free by ds_read_b128.
//   wq_swz: tiles (bn 0..11, kt 0..7), B[e][k] = wqkv[k][e]
//   wp_swz: tiles (bn 0..3,  kt 0..7), B[c][f] = wproj[f][c]
// ===========================================================================
__global__ void convert_weights_swz(const float* __restrict__ wqkv,
                                    const float* __restrict__ wproj,
                                    u16* __restrict__ wq_swz,
                                    u16* __restrict__ wp_swz){
  int c = blockIdx.x * 256 + threadIdx.x;
  union { u16 u[8]; uint4 v; } t;
  if (c < 98304){
    int tile = c >> 10, row = (c >> 3) & 127, c7 = c & 7;
    int bn = tile >> 3, kt = tile & 7;
    int j  = c7 ^ (row & 7);
    int e  = bn * 128 + row;
    int k0 = kt * 64 + j * 8;
    #pragma unroll
    for (int i = 0; i < 8; ++i) t.u[i] = f2bf(wqkv[(long)(k0 + i) * 1536 + e]);
    *reinterpret_cast<uint4*>(wq_swz + (long)c * 8) = t.v;
  } else {
    int c2 = c - 98304;
    int tile = c2 >> 10, row = (c2 >> 3) & 127, c7 = c2 & 7;
    int bn = tile >> 3, kt = tile & 7;
    int j  = c7 ^ (row & 7);
    int e  = bn * 128 + row;
    int k0 = kt * 64 + j * 8;
    #pragma unroll
    for (int i = 0; i < 8; ++i) t.u[i] = f2bf(wproj[(long)(k0 + i) * 512 + e]);
    *reinterpret_cast<uint4*>(wp_swz + (long)c2 * 8) = t.v;
  }
}

// ===========================================================================
// K1: QKV GEMM  qkv[tok][e] = sum_k x[tok][k] * wqkv[k][e] + (bias in epilogue)
// 128x128 tile, BK=64, 4 waves (2x2 of 64x64). A: reg-staged f32->bf16 into
// padded LDS [128][72]. B: global_load_lds from pre-swizzled wq_swz.
// Epilogue: LDS roundtrip -> coalesced 128B bf16 row writes.
// ===========================================================================
__global__ __launch_bounds__(256) void qkv_gemm(
    const float* __restrict__ x,
    const u16*  __restrict__ wswz,
    const float* __restrict__ bqkv,
    u16* __restrict__ qkv)
{
  __shared__ char smem[34816];
  u16*  ldsA = (u16*)smem;          // [128][72] u16, 144B rows (16B aligned)
  char* ldsB = smem + 18432;        // [128] x 128B swizzled rows
  u16*  ldsC = (u16*)smem;          // [128][136] u16, 272B rows

  // XCD-chunked remap: 12288 blocks, 1536/XCD; 12 col-blocks share an A-panel
  int hb   = blockIdx.x;
  int work = (hb & 7) * 1536 + (hb >> 3);
  int bn   = work % 12;
  int bm   = work / 12;

  const int tid = threadIdx.x;
  const int l = tid & 63, w = tid >> 6;
  const int g = l >> 4,  ln = l & 15;
  const int wm = w >> 1, wn = w & 1;

  f32x4 acc[4][4];
  #pragma unroll
  for (int m = 0; m < 4; ++m)
    #pragma unroll
    for (int n = 0; n < 4; ++n) acc[m][n] = (f32x4){0.f,0.f,0.f,0.f};

  const int sr = tid >> 1, sh = tid & 1;           // staging row / half
  const float* xrow = x + (long)(bm*128 + sr) * 512 + sh * 32;
  const u16* bbase  = wswz + (long)(bn * 8) * 8192;

  for (int kt = 0; kt < 8; ++kt){
    __syncthreads();
    // stage A: 32KB f32 -> 16KB bf16 (8 float4 loads, 8 uint2 LDS writes/thr)
    {
      const float4* src = reinterpret_cast<const float4*>(xrow + kt * 64);
      char* dst = (char*)ldsA + sr * 144 + sh * 64;
      #pragma unroll
      for (int i = 0; i < 8; ++i){
        float4 v = src[i];
        uint2 pk;
        pk.x = (u32)f2bf(v.x) | ((u32)f2bf(v.y) << 16);
        pk.y = (u32)f2bf(v.z) | ((u32)f2bf(v.w) << 16);
        *reinterpret_cast<uint2*>(dst + i * 8) = pk;
      }
    }
    // stage B: 16KB via 4 global_load_lds issues (linear; global pre-swizzled)
    {
      const char* gsrc = (const char*)(bbase + (long)kt * 8192);
      #pragma unroll
      for (int i = 0; i < 4; ++i)
        gload16(gsrc + (i*256 + tid) * 16, ldsB + (i*256 + w*64) * 16);
    }
    __syncthreads();
    // compute: 2 k-slices x 16 MFMA
    #pragma unroll
    for (int ks = 0; ks < 2; ++ks){
      short8 a[4], b[4];
      #pragma unroll
      for (int m = 0; m < 4; ++m){
        int row = wm*64 + m*16 + ln;
        a[m] = *reinterpret_cast<const short8*>((const char*)ldsA + row*144 + ks*64 + g*16);
      }
      #pragma unroll
      for (int n = 0; n < 4; ++n){
        int row = wn*64 + n*16 + ln;
        b[n] = *reinterpret_cast<const short8*>(ldsB + row*128 + (((ks*4 + g) ^ (row & 7)) << 4));
      }
      #pragma unroll
      for (int m = 0; m < 4; ++m)
        #pragma unroll
        for (int n = 0; n < 4; ++n)
          acc[m][n] = __builtin_amdgcn_mfma_f32_16x16x32_bf16(a[m], b[n], acc[m][n], 0, 0, 0);
    }
  }

  // epilogue: bias + bf16 via LDS roundtrip, coalesced 128B global rows
  __syncthreads();
  #pragma unroll
  for (int n = 0; n < 4; ++n){
    int col  = wn*64 + n*16 + ln;
    float bias = bqkv[bn*128 + col];
    #pragma unroll
    for (int m = 0; m < 4; ++m){
      int r0 = wm*64 + m*16 + g*4;
      #pragma unroll
      for (int r = 0; r < 4; ++r)
        ldsC[(r0 + r) * 136 + col] = f2bf(acc[m][n][r] + bias);
    }
  }
  __syncthreads();
  {
    int row = tid >> 1, half = tid & 1;
    const char* src = (const char*)(ldsC + row * 136 + half * 64);
    char* dst = (char*)qkv + ((long)(bm*128 + row) * 1536 + bn*128 + half*64) * 2;
    #pragma unroll
    for (int j = 0; j < 8; ++j)
      *reinterpret_cast<uint4*>(dst + j*16) = *reinterpret_cast<const uint4*>(src + j*16);
  }
}

// ===========================================================================
// K2: per-window attention, zero barriers. 4 waves/block, wave = 2 heads.
// Q/K MFMA fragments loaded directly from global qkv rows; V transposed into
// wave-private swizzled LDS; softmax in-register; O -> pre-swizzled obuf
// tiles (so K3 can global_load_lds them).
// ===========================================================================
__global__ __launch_bounds__(256) void winattn(
    const u16* __restrict__ qkv,
    u16* __restrict__ obuf)
{
  __shared__ u16 lds[4][2][4096];    // [wave][0=Vt,1=P/O][64*64]
  const int tid = threadIdx.x;
  const int l = tid & 63, w = tid >> 6;
  const int g = l >> 4,  ln = l & 15;
  const int win = blockIdx.x;
  const long tokb = (long)win * 64;
  u16* vt = lds[w][0];
  u16* pp = lds[w][1];

  const int mt = win >> 1;            // 128-row obuf tile
  const int rbase = (win & 1) * 64;

  for (int it = 0; it < 2; ++it){
    int h = w * 2 + it;
    // ---- Q/K fragments direct from global ----
    short8 qa[4][2], kb[4][2];
    #pragma unroll
    for (int m = 0; m < 4; ++m){
      const char* qrow = (const char*)(qkv + (tokb + m*16 + ln) * 1536 + h*64 + g*8);
      const char* krow = (const char*)(qkv + (tokb + m*16 + ln) * 1536 + 512 + h*64 + g*8);
      qa[m][0] = *reinterpret_cast<const short8*>(qrow);
      qa[m][1] = *reinterpret_cast<const short8*>(qrow + 64);
      kb[m][0] = *reinterpret_cast<const short8*>(krow);
      kb[m][1] = *reinterpret_cast<const short8*>(krow + 64);
    }
    // ---- V load (4 tok x 16 d per lane) ----
    const int dg = l & 3, tg = l >> 2;
    uint4 vr[4][2];
    #pragma unroll
    for (int r = 0; r < 4; ++r){
      const char* vrow = (const char*)(qkv + (tokb + tg*4 + r) * 1536 + 1024 + h*64 + dg*16);
      vr[r][0] = *reinterpret_cast<const uint4*>(vrow);
      vr[r][1] = *reinterpret_cast<const uint4*>(vrow + 16);
    }
    // ---- S = Q K^T ----
    f32x4 sacc[4][4];
    #pragma unroll
    for (int m = 0; m < 4; ++m)
      #pragma unroll
      for (int n = 0; n < 4; ++n) sacc[m][n] = (f32x4){0.f,0.f,0.f,0.f};
    #pragma unroll
    for (int ks = 0; ks < 2; ++ks)
      #pragma unroll
      for (int m = 0; m < 4; ++m)
        #pragma unroll
        for (int n = 0; n < 4; ++n)
          sacc[m][n] = __builtin_amdgcn_mfma_f32_16x16x32_bf16(qa[m][ks], kb[n][ks], sacc[m][n], 0, 0, 0);
    // ---- Vt scatter into swizzled LDS ----
    #pragma unroll
    for (int dd = 0; dd < 16; ++dd){
      int d = dg*16 + dd;
      int sub = dd & 7, hh = dd >> 3;
      uint2 pk;
      pk.x = (u32)((const u16*)&vr[0][hh])[sub] | ((u32)((const u16*)&vr[1][hh])[sub] << 16);
      pk.y = (u32)((const u16*)&vr[2][hh])[sub] | ((u32)((const u16*)&vr[3][hh])[sub] << 16);
      *reinterpret_cast<uint2*>((char*)vt + d*128 + swz(d, tg*8)) = pk;
    }
    // ---- softmax (rows spread over 16 lanes x 4 in-lane frags) ----
    #pragma unroll
    for (int m = 0; m < 4; ++m){
      #pragma unroll
      for (int r = 0; r < 4; ++r){
        float mx = fmaxf(fmaxf(sacc[m][0][r], sacc[m][1][r]), fmaxf(sacc[m][2][r], sacc[m][3][r]));
        mx = fmaxf(mx, __shfl_xor(mx, 1, 64));
        mx = fmaxf(mx, __shfl_xor(mx, 2, 64));
        mx = fmaxf(mx, __shfl_xor(mx, 4, 64));
        mx = fmaxf(mx, __shfl_xor(mx, 8, 64));
        float p[4], s = 0.f;
        #pragma unroll
        for (int n = 0; n < 4; ++n){
          p[n] = __expf((sacc[m][n][r] - mx) * 0.125f);
          s += p[n];
        }
        s += __shfl_xor(s, 1, 64);
        s += __shfl_xor(s, 2, 64);
        s += __shfl_xor(s, 4, 64);
        s += __shfl_xor(s, 8, 64);
        float inv = 1.f / s;
        int i = m*16 + g*4 + r;
        #pragma unroll
        for (int n = 0; n < 4; ++n){
          int c = n*16 + ln;
          *reinterpret_cast<u16*>((char*)pp + i*128 + swz(i, c*2)) = f2bf(p[n] * inv);
        }
      }
    }
    // ---- O = P V ----
    f32x4 oacc[4][4];
    #pragma unroll
    for (int m = 0; m < 4; ++m)
      #pragma unroll
      for (int n = 0; n < 4; ++n) oacc[m][n] = (f32x4){0.f,0.f,0.f,0.f};
    #pragma unroll
    for (int ks = 0; ks < 2; ++ks){
      short8 pa[4], vb[4];
      #pragma unroll
      for (int m = 0; m < 4; ++m){
        int row = m*16 + ln;
        pa[m] = *reinterpret_cast<const short8*>((char*)pp + row*128 + swz(row, (ks*32 + g*8)*2));
      }
      #pragma unroll
      for (int n = 0; n < 4; ++n){
        int row = n*16 + ln;
        vb[n] = *reinterpret_cast<const short8*>((char*)vt + row*128 + swz(row, (ks*32 + g*8)*2));
      }
      #pragma unroll
      for (int m = 0; m < 4; ++m)
        #pragma unroll
        for (int n = 0; n < 4; ++n)
          oacc[m][n] = __builtin_amdgcn_mfma_f32_16x16x32_bf16(pa[m], vb[n], oacc[m][n], 0, 0, 0);
    }
    // ---- O -> lds (reuse P region, row-major swizzled) ----
    #pragma unroll
    for (int m = 0; m < 4; ++m)
      #pragma unroll
      for (int n = 0; n < 4; ++n){
        int d = n*16 + ln;
        #pragma unroll
        for (int r = 0; r < 4; ++r){
          int t = m*16 + g*4 + r;
          *reinterpret_cast<u16*>((char*)pp + t*128 + swz(t, d*2)) = f2bf(oacc[m][n][r]);
        }
      }
    // ---- lds -> obuf pre-swizzled tile (head h = k-tile h of K3) ----
    {
      int row = rbase + l;
      const char* src = (const char*)pp + l*128;
      char* dst = (char*)obuf + ((long)(mt*8 + h) * 128 + row) * 128;
      #pragma unroll
      for (int jj = 0; jj < 8; ++jj){
        uint4 v = *reinterpret_cast<const uint4*>(src + ((jj*16) ^ ((l & 7) << 4)));
        *reinterpret_cast<uint4*>(dst + ((jj ^ (row & 7)) << 4)) = v;
      }
    }
  }
}

// ===========================================================================
// K3: proj GEMM  out[tok][c] = sum_d O[tok][d] * wproj[d][c] + bias, f32 out.
// Both operands via global_load_lds from pre-swizzled tiles.
// ===========================================================================
__global__ __launch_bounds__(256) void proj_gemm(
    const u16* __restrict__ aswz,
    const u16* __restrict__ wswz,
    const float* __restrict__ bproj,
    float* __restrict__ out)
{
  __shared__ char smem[32768];
  char* ldsA = smem;
  char* ldsB = smem + 16384;

  int hb   = blockIdx.x;
  int work = (hb & 7) * 512 + (hb >> 3);
  int bn   = work & 3;
  int bm   = work >> 2;

  const int tid = threadIdx.x;
  const int l = tid & 63, w = tid >> 6;
  const int g = l >> 4,  ln = l & 15;
  const int wm = w >> 1, wn = w & 1;

  f32x4 acc[4][4];
  #pragma unroll
  for (int m = 0; m < 4; ++m)
    #pragma unroll
    for (int n = 0; n < 4; ++n) acc[m][n] = (f32x4){0.f,0.f,0.f,0.f};

  const char* abase = (const char*)aswz + (long)(bm * 8) * 16384;
  const char* bbase = (const char*)wswz + (long)(bn * 8) * 16384;

  for (int kt = 0; kt < 8; ++kt){
    __syncthreads();
    #pragma unroll
    for (int i = 0; i < 4; ++i){
      gload16(abase + (long)kt*16384 + (i*256 + tid)*16, ldsA + (i*256 + w*64)*16);
      gload16(bbase + (long)kt*16384 + (i*256 + tid)*16, ldsB + (i*256 + w*64)*16);
    }
    __syncthreads();
    #pragma unroll
    for (int ks = 0; ks < 2; ++ks){
      short8 a[4], b[4];
      #pragma unroll
      for (int m = 0; m < 4; ++m){
        int row = wm*64 + m*16 + ln;
        a[m] = *reinterpret_cast<const short8*>(ldsA + row*128 + (((ks*4 + g) ^ (row & 7)) << 4));
      }
      #pragma unroll
      for (int n = 0; n < 4; ++n){
        int row = wn*64 + n*16 + ln;
        b[n] = *reinterpret_cast<const short8*>(ldsB + row*128 + (((ks*4 + g) ^ (row & 7)) << 4));
      }
      #pragma unroll
      for (int m = 0; m < 4; ++m)
        #pragma unroll
        for (int n = 0; n < 4; ++n)
          acc[m][n] = __builtin_amdgcn_mfma_f32_16x16x32_bf16(a[m], b[n], acc[m][n], 0, 0, 0);
    }
  }
  // epilogue: direct coalesced f32 stores (16 lanes x 4B = 64B rows)
  #pragma unroll
  for (int n = 0; n < 4; ++n){
    int col = bn*128 + wn*64 + n*16 + ln;
    float bias = bproj[col];
    #pragma unroll
    for (int m = 0; m < 4; ++m){
      long tok = (long)bm*128 + wm*64 + m*16 + g*4;
      #pragma unroll
      for (int r = 0; r < 4; ++r)
        out[(tok + r) * 512 + col] = acc[m][n][r] + bias;
    }
  }
}

// ===========================================================================
// Fallback (round-1 fused kernel) for small ws_size
// ===========================================================================
__global__ void convert_weights(const float* __restrict__ wqkv,
                                const float* __restrict__ wproj,
                                u16* __restrict__ wqkvt,
                                u16* __restrict__ wprojt){
  int tid = blockIdx.x * 256 + threadIdx.x;
  union { u16 u[8]; uint4 v; } tmp;
  if (tid < 1536 * 64){
    int e  = tid >> 6;
    int kc = (tid & 63) << 3;
    #pragma unroll
    for (int i = 0; i < 8; ++i) tmp.u[i] = f2bf(wqkv[(long)(kc + i) * 1536 + e]);
    *reinterpret_cast<uint4*>(wqkvt + (long)e * 512 + kc) = tmp.v;
  } else {
    int t2 = tid - 1536 * 64;
    int c  = t2 >> 6;
    int kc = (t2 & 63) << 3;
    #pragma unroll
    for (int i = 0; i < 8; ++i) tmp.u[i] = f2bf(wproj[(long)(kc + i) * 512 + c]);
    *reinterpret_cast<uint4*>(wprojt + (long)c * 512 + kc) = tmp.v;
  }
}

__global__ __launch_bounds__(512, 2) void fused_winattn(
    const float* __restrict__ x,
    const u16*  __restrict__ wqkvt,
    const float* __restrict__ bqkv,
    const u16*  __restrict__ wprojt,
    const float* __restrict__ bproj,
    float* __restrict__ out)
{
  __shared__ u16 lds_x[64 * 512];
  __shared__ u16 lds_q[64 * 64];
  __shared__ u16 lds_k[64 * 64];
  __shared__ u16 lds_vt[64 * 64];
  __shared__ u16 lds_p[64 * 64];

  const int tid = threadIdx.x;
  const int l   = tid & 63;
  const int w   = tid >> 6;
  const int g   = l >> 4;
  const int ln  = l & 15;
  const long tokbase = (long)blockIdx.x * 64;

  {
    const float4* xv = reinterpret_cast<const float4*>(x + tokbase * 512);
    #pragma unroll
    for (int j = 0; j < 16; ++j){
      int i   = j * 512 + tid;
      int row = i >> 7;
      int c4  = i & 127;
      float4 v = xv[i];
      uint2 pk;
      pk.x = (u32)f2bf(v.x) | ((u32)f2bf(v.y) << 16);
      pk.y = (u32)f2bf(v.z) | ((u32)f2bf(v.w) << 16);
      int byte = row * 1024 + swz(row, c4 * 8);
      *reinterpret_cast<uint2*>(reinterpret_cast<char*>(lds_x) + byte) = pk;
    }
  }

  f32x4 oacc[4][4];
  #pragma unroll
  for (int m = 0; m < 4; ++m)
    #pragma unroll
    for (int n = 0; n < 4; ++n) oacc[m][n] = (f32x4){0.f, 0.f, 0.f, 0.f};

  const int mw   = w & 3;
  const int half = w >> 2;

  __syncthreads();

  for (int h = 0; h < 8; ++h){
    f32x4 qacc[6];
    #pragma unroll
    for (int j = 0; j < 6; ++j) qacc[j] = (f32x4){0.f, 0.f, 0.f, 0.f};
    int ebase[6];
    #pragma unroll
    for (int j = 0; j < 6; ++j){
      int nt = half * 6 + j;
      int sec = nt >> 2;
      ebase[j] = sec * 512 + h * 64 + (nt & 3) * 16;
    }
    const int arow = mw * 16 + ln;
    #pragma unroll
    for (int ks = 0; ks < 16; ++ks){
      short8 a = *reinterpret_cast<const short8*>(
          reinterpret_cast<const char*>(lds_x) + arow * 1024 + swz(arow, (ks * 32 + g * 8) * 2));
      #pragma unroll
      for (int j = 0; j < 6; ++j){
        short8 b = *reinterpret_cast<const short8*>(
            wqkvt + (long)(ebase[j] + ln) * 512 + ks * 32 + g * 8);
        qacc[j] = __builtin_amdgcn_mfma_f32_16x16x32_bf16(a, b, qacc[j], 0, 0, 0);
      }
    }
    #pragma unroll
    for (int j = 0; j < 6; ++j){
      int nt  = half * 6 + j;
      int sec = nt >> 2;
      float bias = bqkv[ebase[j] + ln];
      if (sec < 2){
        u16* dst = (sec == 0) ? lds_q : lds_k;
        int c = (nt & 3) * 16 + ln;
        #pragma unroll
        for (int r = 0; r < 4; ++r){
          int t = mw * 16 + g * 4 + r;
          int byte = t * 128 + swz(t, c * 2);
          *reinterpret_cast<u16*>(reinterpret_cast<char*>(dst) + byte) = f2bf(qacc[j][r] + bias);
        }
      } else {
        int d  = (nt & 3) * 16 + ln;
        int t0 = mw * 16 + g * 4;
        uint2 pk;
        pk.x = (u32)f2bf(qacc[j][0] + bias) | ((u32)f2bf(qacc[j][1] + bias) << 16);
        pk.y = (u32)f2bf(qacc[j][2] + bias) | ((u32)f2bf(qacc[j][3] + bias) << 16);
        int byte = d * 128 + swz(d, t0 * 2);
        *reinterpret_cast<uint2*>(reinterpret_cast<char*>(lds_vt) + byte) = pk;
      }
    }
    __syncthreads();

    if (w < 4){
      f32x4 sacc[4];
      #pragma unroll
      for (int jt = 0; jt < 4; ++jt) sacc[jt] = (f32x4){0.f, 0.f, 0.f, 0.f};
      #pragma unroll
      for (int ks = 0; ks < 2; ++ks){
        int qrow = w * 16 + ln;
        short8 a = *reinterpret_cast<const short8*>(
            reinterpret_cast<const char*>(lds_q) + qrow * 128 + swz(qrow, (ks * 32 + g * 8) * 2));
        #pragma unroll
        for (int jt = 0; jt < 4; ++jt){
          int krow = jt * 16 + ln;
          short8 b = *reinterpret_cast<const short8*>(
              reinterpret_cast<const char*>(lds_k) + krow * 128 + swz(krow, (ks * 32 + g * 8) * 2));
          sacc[jt] = __builtin_amdgcn_mfma_f32_16x16x32_bf16(a, b, sacc[jt], 0, 0, 0);
        }
      }
      #pragma unroll
      for (int r = 0; r < 4; ++r){
        float mx = fmaxf(fmaxf(sacc[0][r], sacc[1][r]), fmaxf(sacc[2][r], sacc[3][r]));
        mx = fmaxf(mx, __shfl_xor(mx, 1, 64));
        mx = fmaxf(mx, __shfl_xor(mx, 2, 64));
        mx = fmaxf(mx, __shfl_xor(mx, 4, 64));
        mx = fmaxf(mx, __shfl_xor(mx, 8, 64));
        float p[4], s = 0.f;
        #pragma unroll
        for (int jt = 0; jt < 4; ++jt){
          p[jt] = __expf((sacc[jt][r] - mx) * 0.125f);
          s += p[jt];
        }
        s += __shfl_xor(s, 1, 64);
        s += __shfl_xor(s, 2, 64);
        s += __shfl_xor(s, 4, 64);
        s += __shfl_xor(s, 8, 64);
        float inv = 1.f / s;
        int i = w * 16 + g * 4 + r;
        #pragma unroll
        for (int jt = 0; jt < 4; ++jt){
          int c = jt * 16 + ln;
          int byte = i * 128 + swz(i, c * 2);
          *reinterpret_cast<u16*>(reinterpret_cast<char*>(lds_p) + byte) = f2bf(p[jt] * inv);
        }
      }
    }
    __syncthreads();

    {
      int mc  = w & 3;
      int nc0 = (w >> 2) * 2;
      f32x4 oc[2];
      oc[0] = (f32x4){0.f, 0.f, 0.f, 0.f};
      oc[1] = (f32x4){0.f, 0.f, 0.f, 0.f};
      #pragma unroll
      for (int ks = 0; ks < 2; ++ks){
        int prow = mc * 16 + ln;
        short8 a = *reinterpret_cast<const short8*>(
            reinterpret_cast<const char*>(lds_p) + prow * 128 + swz(prow, (ks * 32 + g * 8) * 2));
        #pragma unroll
        for (int jj = 0; jj < 2; ++jj){
          int vrow = (nc0 + jj) * 16 + ln;
          short8 b = *reinterpret_cast<const short8*>(
              reinterpret_cast<const char*>(lds_vt) + vrow * 128 + swz(vrow, (ks * 32 + g * 8) * 2));
          oc[jj] = __builtin_amdgcn_mfma_f32_16x16x32_bf16(a, b, oc[jj], 0, 0, 0);
        }
      }
      #pragma unroll
      for (int jj = 0; jj < 2; ++jj){
        int d = (nc0 + jj) * 16 + ln;
        #pragma unroll
        for (int r = 0; r < 4; ++r){
          int t = mc * 16 + g * 4 + r;
          int byte = t * 128 + swz(t, d * 2);
          *reinterpret_cast<u16*>(reinterpret_cast<char*>(lds_q) + byte) = f2bf(oc[jj][r]);
        }
      }
    }
    __syncthreads();

    #pragma unroll
    for (int ks = 0; ks < 2; ++ks){
      short8 a[4];
      #pragma unroll
      for (int m = 0; m < 4; ++m){
        int row = m * 16 + ln;
        a[m] = *reinterpret_cast<const short8*>(
            reinterpret_cast<const char*>(lds_q) + row * 128 + swz(row, (ks * 32 + g * 8) * 2));
      }
      #pragma unroll
      for (int nt = 0; nt < 4; ++nt){
        int e = w * 64 + nt * 16 + ln;
        short8 b = *reinterpret_cast<const short8*>(
            wprojt + (long)e * 512 + h * 64 + ks * 32 + g * 8);
        #pragma unroll
        for (int m = 0; m < 4; ++m)
          oacc[m][nt] = __builtin_amdgcn_mfma_f32_16x16x32_bf16(a[m], b, oacc[m][nt], 0, 0, 0);
      }
    }
    __syncthreads();
  }

  #pragma unroll
  for (int nt = 0; nt < 4; ++nt){
    int col = w * 64 + nt * 16 + ln;
    float bias = bproj[col];
    #pragma unroll
    for (int m = 0; m < 4; ++m){
      #pragma unroll
      for (int r = 0; r < 4; ++r){
        int t = m * 16 + g * 4 + r;
        out[(tokbase + t) * 512 + col] = oacc[m][nt][r] + bias;
      }
    }
  }
}

extern "C" void kernel_launch(void* const* d_in, const int* in_sizes, int n_in,
                              void* d_out, int out_size, void* d_ws, size_t ws_size,
                              hipStream_t stream) {
  const float* x     = (const float*)d_in[0];
  const float* wqkv  = (const float*)d_in[1];
  const float* bqkv  = (const float*)d_in[2];
  const float* wproj = (const float*)d_in[3];
  const float* bproj = (const float*)d_in[4];
  float* out = (float*)d_out;

  const size_t NEED = 538968064ULL;   // wq 1.5M + wp 0.5M + qkv 384M + obuf 128M
  if (ws_size >= NEED){
    u16* wq_swz = (u16*)d_ws;
    u16* wp_swz = (u16*)((char*)d_ws + 1572864);
    u16* qkv    = (u16*)((char*)d_ws + 2097152);
    u16* obuf   = (u16*)((char*)d_ws + 404750336);
    convert_weights_swz<<<512, 256, 0, stream>>>(wqkv, wproj, wq_swz, wp_swz);
    qkv_gemm<<<12288, 256, 0, stream>>>(x, wq_swz, bqkv, qkv);
    winattn<<<2048, 256, 0, stream>>>(qkv, obuf);
    proj_gemm<<<4096, 256, 0, stream>>>(obuf, wp_swz, bproj, out);
  } else {
    u16* wqkvt  = (u16*)d_ws;
    u16* wprojt = wqkvt + 1536 * 512;
    convert_weights<<<512, 256, 0, stream>>>(wqkv, wproj, wqkvt, wprojt);
    fused_winattn<<<2048, 512, 0, stream>>>(x, wqkvt, bqkv, wprojt, bproj, out);
  }
}

// Round 3
// 686.231 us; speedup vs baseline: 2.5465x; 1.3310x over previous
//
#include <hip/hip_runtime.h>

typedef __attribute__((ext_vector_type(8))) short short8;
typedef __attribute__((ext_vector_type(4))) float f32x4;
typedef unsigned short u16;
typedef unsigned int u32;

// round-to-nearest-even f32 -> bf16
__device__ __forceinline__ u16 f2bf(float f){
  union { float f; u32 u; } v; v.f = f;
  u32 u = v.u;
  u32 r = (u + 0x7FFFu + ((u >> 16) & 1u)) >> 16;
  return (u16)r;
}

// XOR swizzle on byte-in-row (bits 4..6) to break power-of-2 row strides
__device__ __forceinline__ int swz(int row, int cb){ return cb ^ ((row & 7) << 4); }

// async global->LDS 16B copy (wave-uniform LDS base, lane-strided dest)
__device__ __forceinline__ void gload16(const void* g, void* l){
  __builtin_amdgcn_global_load_lds(
      (const __attribute__((address_space(1))) unsigned int*)g,
      (__attribute__((address_space(3))) unsigned int*)l, 16, 0, 0);
}

// ===========================================================================
// K0: weights.  wq_swz = wqkv^T in pre-swizzled 128x64 bf16 tiles (for
// global_load_lds staging); wpt = plain transposed wproj (wpt[c][f]) for
// direct global B-fragment reads in the fused attention+proj kernel.
// Tile chunk convention: 16B chunk (row, c7) of tile holds logical
// B[row][(c7 ^ (row&7))*8 .. +8) so a LINEAR LDS image is read conflict-free
// by ds_read_b128 at byte row*128 + ((j8 ^ (row&7))<<4).
// ===========================================================================
__global__ void convert_weights_swz(const float* __restrict__ wqkv,
                                    const float* __restrict__ wproj,
                                    u16* __restrict__ wq_swz,
                                    u16* __restrict__ wpt){
  int c = blockIdx.x * 256 + threadIdx.x;
  union { u16 u[8]; uint4 v; } t;
  if (c < 98304){
    int tile = c >> 10, row = (c >> 3) & 127, c7 = c & 7;
    int bn = tile >> 3, kt = tile & 7;
    int j  = c7 ^ (row & 7);
    int e  = bn * 128 + row;
    int k0 = kt * 64 + j * 8;
    #pragma unroll
    for (int i = 0; i < 8; ++i) t.u[i] = f2bf(wqkv[(long)(k0 + i) * 1536 + e]);
    *reinterpret_cast<uint4*>(wq_swz + (long)c * 8) = t.v;
  } else {
    int t2 = c - 98304;
    int cc = t2 >> 6;
    int kc = (t2 & 63) << 3;
    #pragma unroll
    for (int i = 0; i < 8; ++i) t.u[i] = f2bf(wproj[(long)(kc + i) * 512 + cc]);
    *reinterpret_cast<uint4*>(wpt + (long)cc * 512 + kc) = t.v;
  }
}

// ===========================================================================
// K0b: x f32 -> bf16 pre-swizzled 128x64 tiles (same chunk convention).
// Tile (bm, kt) at xbf + (bm*8 + kt)*8192 u16.
// ===========================================================================
__global__ void convert_x(const float* __restrict__ x, u16* __restrict__ xbf){
  int c = blockIdx.x * 256 + threadIdx.x;      // chunk id, 8.39M total
  int tile = c >> 10, row = (c >> 3) & 127, c7 = c & 7;
  int bm = tile >> 3, kt = tile & 7;
  int j  = c7 ^ (row & 7);
  const float* src = x + (long)(bm * 128 + row) * 512 + kt * 64 + j * 8;
  float4 v0 = *reinterpret_cast<const float4*>(src);
  float4 v1 = *reinterpret_cast<const float4*>(src + 4);
  union { u16 u[8]; uint4 v; } t;
  t.u[0] = f2bf(v0.x); t.u[1] = f2bf(v0.y); t.u[2] = f2bf(v0.z); t.u[3] = f2bf(v0.w);
  t.u[4] = f2bf(v1.x); t.u[5] = f2bf(v1.y); t.u[6] = f2bf(v1.z); t.u[7] = f2bf(v1.w);
  *reinterpret_cast<uint4*>(xbf + (long)c * 8) = t.v;
}

// ===========================================================================
// K1: QKV GEMM  qkv[tok][e] = sum_k x[tok][k]*wqkv[k][e] + bias(epilogue).
// 128x128 tile, BK=64, 4 waves (2x2 of 64x64). BOTH operands staged via
// global_load_lds from pre-swizzled tiles (m97 structure, 2 barriers/K-step).
// ===========================================================================
__global__ __launch_bounds__(256) void qkv_gemm(
    const u16*  __restrict__ xbf,
    const u16*  __restrict__ wswz,
    const float* __restrict__ bqkv,
    u16* __restrict__ qkv)
{
  __shared__ char smem[34816];
  char* ldsA = smem;               // 16 KB swizzled A tile image
  char* ldsB = smem + 16384;       // 16 KB swizzled B tile image
  u16*  ldsC = (u16*)smem;         // epilogue: [128][136] u16

  // XCD-chunked remap: 12288 blocks, 1536/XCD; 12 n-blocks share an A-panel
  int hb   = blockIdx.x;
  int work = (hb & 7) * 1536 + (hb >> 3);
  int bn   = work % 12;
  int bm   = work / 12;

  const int tid = threadIdx.x;
  const int l = tid & 63, w = tid >> 6;
  const int g = l >> 4,  ln = l & 15;
  const int wm = w >> 1, wn = w & 1;

  f32x4 acc[4][4];
  #pragma unroll
  for (int m = 0; m < 4; ++m)
    #pragma unroll
    for (int n = 0; n < 4; ++n) acc[m][n] = (f32x4){0.f,0.f,0.f,0.f};

  const char* abase = (const char*)(xbf  + (long)(bm * 8) * 8192);
  const char* bbase = (const char*)(wswz + (long)(bn * 8) * 8192);

  for (int kt = 0; kt < 8; ++kt){
    __syncthreads();
    #pragma unroll
    for (int i = 0; i < 4; ++i){
      gload16(abase + (long)kt*16384 + (i*256 + tid)*16, ldsA + (i*256 + w*64)*16);
      gload16(bbase + (long)kt*16384 + (i*256 + tid)*16, ldsB + (i*256 + w*64)*16);
    }
    __syncthreads();
    #pragma unroll
    for (int ks = 0; ks < 2; ++ks){
      short8 a[4], b[4];
      #pragma unroll
      for (int m = 0; m < 4; ++m){
        int row = wm*64 + m*16 + ln;
        a[m] = *reinterpret_cast<const short8*>(ldsA + row*128 + (((ks*4 + g) ^ (row & 7)) << 4));
      }
      #pragma unroll
      for (int n = 0; n < 4; ++n){
        int row = wn*64 + n*16 + ln;
        b[n] = *reinterpret_cast<const short8*>(ldsB + row*128 + (((ks*4 + g) ^ (row & 7)) << 4));
      }
      #pragma unroll
      for (int m = 0; m < 4; ++m)
        #pragma unroll
        for (int n = 0; n < 4; ++n)
          acc[m][n] = __builtin_amdgcn_mfma_f32_16x16x32_bf16(a[m], b[n], acc[m][n], 0, 0, 0);
    }
  }

  // epilogue: bias + bf16 via LDS roundtrip, coalesced 128B global rows
  __syncthreads();
  #pragma unroll
  for (int n = 0; n < 4; ++n){
    int col  = wn*64 + n*16 + ln;
    float bias = bqkv[bn*128 + col];
    #pragma unroll
    for (int m = 0; m < 4; ++m){
      int r0 = wm*64 + m*16 + g*4;
      #pragma unroll
      for (int r = 0; r < 4; ++r)
        ldsC[(r0 + r) * 136 + col] = f2bf(acc[m][n][r] + bias);
    }
  }
  __syncthreads();
  {
    int row = tid >> 1, half = tid & 1;
    const char* src = (const char*)(ldsC + row * 136 + half * 64);
    char* dst = (char*)qkv + ((long)(bm*128 + row) * 1536 + bn*128 + half*64) * 2;
    #pragma unroll
    for (int j = 0; j < 8; ++j)
      *reinterpret_cast<uint4*>(dst + j*16) = *reinterpret_cast<const uint4*>(src + j*16);
  }
}

// ===========================================================================
// K2: fused window attention + output projection.
// One block = one 64-token window, 8 waves; wave w owns head w end-to-end:
//   S = Q K^T, softmax, O_w = P V  (Q/K frags direct from global qkv rows,
//   V transposed into wave-private swizzled LDS, P via swizzled LDS)
// then ONE barrier, then every wave accumulates its 64-col slice of
// out = O @ wproj + bias over all 8 heads' O tiles in LDS.
// ===========================================================================
__global__ __launch_bounds__(512, 2) void winattn_proj(
    const u16* __restrict__ qkv,
    const u16* __restrict__ wpt,
    const float* __restrict__ bproj,
    float* __restrict__ out)
{
  __shared__ u16 lds[8][2][4096];   // [wave][0=Vt, 1=P then O][64*64], 128 KB
  const int tid = threadIdx.x;
  const int l = tid & 63, w = tid >> 6;
  const int g = l >> 4,  ln = l & 15;
  const long tokb = (long)blockIdx.x * 64;
  u16* vt = lds[w][0];
  u16* pp = lds[w][1];
  const int h = w;

  // ---- Q/K fragments direct from global ----
  short8 qa[4][2], kb[4][2];
  #pragma unroll
  for (int m = 0; m < 4; ++m){
    const char* qrow = (const char*)(qkv + (tokb + m*16 + ln) * 1536 + h*64 + g*8);
    const char* krow = (const char*)(qkv + (tokb + m*16 + ln) * 1536 + 512 + h*64 + g*8);
    qa[m][0] = *reinterpret_cast<const short8*>(qrow);
    qa[m][1] = *reinterpret_cast<const short8*>(qrow + 64);
    kb[m][0] = *reinterpret_cast<const short8*>(krow);
    kb[m][1] = *reinterpret_cast<const short8*>(krow + 64);
  }
  // ---- V load (4 tok x 16 d per lane) ----
  const int dg = l & 3, tg = l >> 2;
  uint4 vr[4][2];
  #pragma unroll
  for (int r = 0; r < 4; ++r){
    const char* vrow = (const char*)(qkv + (tokb + tg*4 + r) * 1536 + 1024 + h*64 + dg*16);
    vr[r][0] = *reinterpret_cast<const uint4*>(vrow);
    vr[r][1] = *reinterpret_cast<const uint4*>(vrow + 16);
  }
  // ---- S = Q K^T ----
  f32x4 sacc[4][4];
  #pragma unroll
  for (int m = 0; m < 4; ++m)
    #pragma unroll
    for (int n = 0; n < 4; ++n) sacc[m][n] = (f32x4){0.f,0.f,0.f,0.f};
  #pragma unroll
  for (int ks = 0; ks < 2; ++ks)
    #pragma unroll
    for (int m = 0; m < 4; ++m)
      #pragma unroll
      for (int n = 0; n < 4; ++n)
        sacc[m][n] = __builtin_amdgcn_mfma_f32_16x16x32_bf16(qa[m][ks], kb[n][ks], sacc[m][n], 0, 0, 0);
  // ---- Vt scatter into wave-private swizzled LDS ----
  #pragma unroll
  for (int dd = 0; dd < 16; ++dd){
    int d = dg*16 + dd;
    int sub = dd & 7, hh = dd >> 3;
    uint2 pk;
    pk.x = (u32)((const u16*)&vr[0][hh])[sub] | ((u32)((const u16*)&vr[1][hh])[sub] << 16);
    pk.y = (u32)((const u16*)&vr[2][hh])[sub] | ((u32)((const u16*)&vr[3][hh])[sub] << 16);
    *reinterpret_cast<uint2*>((char*)vt + d*128 + swz(d, tg*8)) = pk;
  }
  // ---- softmax (rows spread over 16 lanes x 4 in-lane frags) ----
  #pragma unroll
  for (int m = 0; m < 4; ++m){
    #pragma unroll
    for (int r = 0; r < 4; ++r){
      float mx = fmaxf(fmaxf(sacc[m][0][r], sacc[m][1][r]), fmaxf(sacc[m][2][r], sacc[m][3][r]));
      mx = fmaxf(mx, __shfl_xor(mx, 1, 64));
      mx = fmaxf(mx, __shfl_xor(mx, 2, 64));
      mx = fmaxf(mx, __shfl_xor(mx, 4, 64));
      mx = fmaxf(mx, __shfl_xor(mx, 8, 64));
      float p[4], s = 0.f;
      #pragma unroll
      for (int n = 0; n < 4; ++n){
        p[n] = __expf((sacc[m][n][r] - mx) * 0.125f);
        s += p[n];
      }
      s += __shfl_xor(s, 1, 64);
      s += __shfl_xor(s, 2, 64);
      s += __shfl_xor(s, 4, 64);
      s += __shfl_xor(s, 8, 64);
      float inv = 1.f / s;
      int i = m*16 + g*4 + r;
      #pragma unroll
      for (int n = 0; n < 4; ++n){
        int c = n*16 + ln;
        *reinterpret_cast<u16*>((char*)pp + i*128 + swz(i, c*2)) = f2bf(p[n] * inv);
      }
    }
  }
  // ---- O = P V ----
  f32x4 oacc[4][4];
  #pragma unroll
  for (int m = 0; m < 4; ++m)
    #pragma unroll
    for (int n = 0; n < 4; ++n) oacc[m][n] = (f32x4){0.f,0.f,0.f,0.f};
  #pragma unroll
  for (int ks = 0; ks < 2; ++ks){
    short8 pa[4], vb[4];
    #pragma unroll
    for (int m = 0; m < 4; ++m){
      int row = m*16 + ln;
      pa[m] = *reinterpret_cast<const short8*>((char*)pp + row*128 + swz(row, (ks*32 + g*8)*2));
    }
    #pragma unroll
    for (int n = 0; n < 4; ++n){
      int row = n*16 + ln;
      vb[n] = *reinterpret_cast<const short8*>((char*)vt + row*128 + swz(row, (ks*32 + g*8)*2));
    }
    #pragma unroll
    for (int m = 0; m < 4; ++m)
      #pragma unroll
      for (int n = 0; n < 4; ++n)
        oacc[m][n] = __builtin_amdgcn_mfma_f32_16x16x32_bf16(pa[m], vb[n], oacc[m][n], 0, 0, 0);
  }
  // ---- O_w -> LDS (reuse P region; row-major [tok][d], swizzled) ----
  #pragma unroll
  for (int m = 0; m < 4; ++m)
    #pragma unroll
    for (int n = 0; n < 4; ++n){
      int d = n*16 + ln;
      #pragma unroll
      for (int r = 0; r < 4; ++r){
        int t = m*16 + g*4 + r;
        *reinterpret_cast<u16*>((char*)pp + t*128 + swz(t, d*2)) = f2bf(oacc[m][n][r]);
      }
    }

  __syncthreads();

  // ---- proj: acc(64 tok x 64 cols, cols w*64..) += O_hh @ wproj_hh ----
  f32x4 acc[4][4];
  #pragma unroll
  for (int m = 0; m < 4; ++m)
    #pragma unroll
    for (int n = 0; n < 4; ++n) acc[m][n] = (f32x4){0.f,0.f,0.f,0.f};

  for (int hh = 0; hh < 8; ++hh){
    const char* obuf = (const char*)lds[hh][1];
    #pragma unroll
    for (int ks = 0; ks < 2; ++ks){
      short8 a[4], b[4];
      #pragma unroll
      for (int m = 0; m < 4; ++m){
        int row = m*16 + ln;
        a[m] = *reinterpret_cast<const short8*>(obuf + row*128 + swz(row, (ks*32 + g*8)*2));
      }
      #pragma unroll
      for (int n = 0; n < 4; ++n){
        int e = w*64 + n*16 + ln;
        b[n] = *reinterpret_cast<const short8*>(wpt + (long)e*512 + hh*64 + ks*32 + g*8);
      }
      #pragma unroll
      for (int m = 0; m < 4; ++m)
        #pragma unroll
        for (int n = 0; n < 4; ++n)
          acc[m][n] = __builtin_amdgcn_mfma_f32_16x16x32_bf16(a[m], b[n], acc[m][n], 0, 0, 0);
    }
  }

  // ---- epilogue: bias + f32 coalesced stores ----
  #pragma unroll
  for (int n = 0; n < 4; ++n){
    int col = w*64 + n*16 + ln;
    float bias = bproj[col];
    #pragma unroll
    for (int m = 0; m < 4; ++m){
      #pragma unroll
      for (int r = 0; r < 4; ++r){
        int t = m*16 + g*4 + r;
        out[(tokb + t) * 512 + col] = acc[m][n][r] + bias;
      }
    }
  }
}

// ===========================================================================
// Fallback (round-1 fused kernel) for small ws_size
// ===========================================================================
__global__ void convert_weights(const float* __restrict__ wqkv,
                                const float* __restrict__ wproj,
                                u16* __restrict__ wqkvt,
                                u16* __restrict__ wprojt){
  int tid = blockIdx.x * 256 + threadIdx.x;
  union { u16 u[8]; uint4 v; } tmp;
  if (tid < 1536 * 64){
    int e  = tid >> 6;
    int kc = (tid & 63) << 3;
    #pragma unroll
    for (int i = 0; i < 8; ++i) tmp.u[i] = f2bf(wqkv[(long)(kc + i) * 1536 + e]);
    *reinterpret_cast<uint4*>(wqkvt + (long)e * 512 + kc) = tmp.v;
  } else {
    int t2 = tid - 1536 * 64;
    int c  = t2 >> 6;
    int kc = (t2 & 63) << 3;
    #pragma unroll
    for (int i = 0; i < 8; ++i) tmp.u[i] = f2bf(wproj[(long)(kc + i) * 512 + c]);
    *reinterpret_cast<uint4*>(wprojt + (long)c * 512 + kc) = tmp.v;
  }
}

__global__ __launch_bounds__(512, 2) void fused_winattn(
    const float* __restrict__ x,
    const u16*  __restrict__ wqkvt,
    const float* __restrict__ bqkv,
    const u16*  __restrict__ wprojt,
    const float* __restrict__ bproj,
    float* __restrict__ out)
{
  __shared__ u16 lds_x[64 * 512];
  __shared__ u16 lds_q[64 * 64];
  __shared__ u16 lds_k[64 * 64];
  __shared__ u16 lds_vt[64 * 64];
  __shared__ u16 lds_p[64 * 64];

  const int tid = threadIdx.x;
  const int l   = tid & 63;
  const int w   = tid >> 6;
  const int g   = l >> 4;
  const int ln  = l & 15;
  const long tokbase = (long)blockIdx.x * 64;

  {
    const float4* xv = reinterpret_cast<const float4*>(x + tokbase * 512);
    #pragma unroll
    for (int j = 0; j < 16; ++j){
      int i   = j * 512 + tid;
      int row = i >> 7;
      int c4  = i & 127;
      float4 v = xv[i];
      uint2 pk;
      pk.x = (u32)f2bf(v.x) | ((u32)f2bf(v.y) << 16);
      pk.y = (u32)f2bf(v.z) | ((u32)f2bf(v.w) << 16);
      int byte = row * 1024 + swz(row, c4 * 8);
      *reinterpret_cast<uint2*>(reinterpret_cast<char*>(lds_x) + byte) = pk;
    }
  }

  f32x4 oacc[4][4];
  #pragma unroll
  for (int m = 0; m < 4; ++m)
    #pragma unroll
    for (int n = 0; n < 4; ++n) oacc[m][n] = (f32x4){0.f, 0.f, 0.f, 0.f};

  const int mw   = w & 3;
  const int half = w >> 2;

  __syncthreads();

  for (int h = 0; h < 8; ++h){
    f32x4 qacc[6];
    #pragma unroll
    for (int j = 0; j < 6; ++j) qacc[j] = (f32x4){0.f, 0.f, 0.f, 0.f};
    int ebase[6];
    #pragma unroll
    for (int j = 0; j < 6; ++j){
      int nt = half * 6 + j;
      int sec = nt >> 2;
      ebase[j] = sec * 512 + h * 64 + (nt & 3) * 16;
    }
    const int arow = mw * 16 + ln;
    #pragma unroll
    for (int ks = 0; ks < 16; ++ks){
      short8 a = *reinterpret_cast<const short8*>(
          reinterpret_cast<const char*>(lds_x) + arow * 1024 + swz(arow, (ks * 32 + g * 8) * 2));
      #pragma unroll
      for (int j = 0; j < 6; ++j){
        short8 b = *reinterpret_cast<const short8*>(
            wqkvt + (long)(ebase[j] + ln) * 512 + ks * 32 + g * 8);
        qacc[j] = __builtin_amdgcn_mfma_f32_16x16x32_bf16(a, b, qacc[j], 0, 0, 0);
      }
    }
    #pragma unroll
    for (int j = 0; j < 6; ++j){
      int nt  = half * 6 + j;
      int sec = nt >> 2;
      float bias = bqkv[ebase[j] + ln];
      if (sec < 2){
        u16* dst = (sec == 0) ? lds_q : lds_k;
        int c = (nt & 3) * 16 + ln;
        #pragma unroll
        for (int r = 0; r < 4; ++r){
          int t = mw * 16 + g * 4 + r;
          int byte = t * 128 + swz(t, c * 2);
          *reinterpret_cast<u16*>(reinterpret_cast<char*>(dst) + byte) = f2bf(qacc[j][r] + bias);
        }
      } else {
        int d  = (nt & 3) * 16 + ln;
        int t0 = mw * 16 + g * 4;
        uint2 pk;
        pk.x = (u32)f2bf(qacc[j][0] + bias) | ((u32)f2bf(qacc[j][1] + bias) << 16);
        pk.y = (u32)f2bf(qacc[j][2] + bias) | ((u32)f2bf(qacc[j][3] + bias) << 16);
        int byte = d * 128 + swz(d, t0 * 2);
        *reinterpret_cast<uint2*>(reinterpret_cast<char*>(lds_vt) + byte) = pk;
      }
    }
    __syncthreads();

    if (w < 4){
      f32x4 sacc[4];
      #pragma unroll
      for (int jt = 0; jt < 4; ++jt) sacc[jt] = (f32x4){0.f, 0.f, 0.f, 0.f};
      #pragma unroll
      for (int ks = 0; ks < 2; ++ks){
        int qrow = w * 16 + ln;
        short8 a = *reinterpret_cast<const short8*>(
            reinterpret_cast<const char*>(lds_q) + qrow * 128 + swz(qrow, (ks * 32 + g * 8) * 2));
        #pragma unroll
        for (int jt = 0; jt < 4; ++jt){
          int krow = jt * 16 + ln;
          short8 b = *reinterpret_cast<const short8*>(
              reinterpret_cast<const char*>(lds_k) + krow * 128 + swz(krow, (ks * 32 + g * 8) * 2));
          sacc[jt] = __builtin_amdgcn_mfma_f32_16x16x32_bf16(a, b, sacc[jt], 0, 0, 0);
        }
      }
      #pragma unroll
      for (int r = 0; r < 4; ++r){
        float mx = fmaxf(fmaxf(sacc[0][r], sacc[1][r]), fmaxf(sacc[2][r], sacc[3][r]));
        mx = fmaxf(mx, __shfl_xor(mx, 1, 64));
        mx = fmaxf(mx, __shfl_xor(mx, 2, 64));
        mx = fmaxf(mx, __shfl_xor(mx, 4, 64));
        mx = fmaxf(mx, __shfl_xor(mx, 8, 64));
        float p[4], s = 0.f;
        #pragma unroll
        for (int jt = 0; jt < 4; ++jt){
          p[jt] = __expf((sacc[jt][r] - mx) * 0.125f);
          s += p[jt];
        }
        s += __shfl_xor(s, 1, 64);
        s += __shfl_xor(s, 2, 64);
        s += __shfl_xor(s, 4, 64);
        s += __shfl_xor(s, 8, 64);
        float inv = 1.f / s;
        int i = w * 16 + g * 4 + r;
        #pragma unroll
        for (int jt = 0; jt < 4; ++jt){
          int c = jt * 16 + ln;
          int byte = i * 128 + swz(i, c * 2);
          *reinterpret_cast<u16*>(reinterpret_cast<char*>(lds_p) + byte) = f2bf(p[jt] * inv);
        }
      }
    }
    __syncthreads();

    {
      int mc  = w & 3;
      int nc0 = (w >> 2) * 2;
      f32x4 oc[2];
      oc[0] = (f32x4){0.f, 0.f, 0.f, 0.f};
      oc[1] = (f32x4){0.f, 0.f, 0.f, 0.f};
      #pragma unroll
      for (int ks = 0; ks < 2; ++ks){
        int prow = mc * 16 + ln;
        short8 a = *reinterpret_cast<const short8*>(
            reinterpret_cast<const char*>(lds_p) + prow * 128 + swz(prow, (ks * 32 + g * 8) * 2));
        #pragma unroll
        for (int jj = 0; jj < 2; ++jj){
          int vrow = (nc0 + jj) * 16 + ln;
          short8 b = *reinterpret_cast<const short8*>(
              reinterpret_cast<const char*>(lds_vt) + vrow * 128 + swz(vrow, (ks * 32 + g * 8) * 2));
          oc[jj] = __builtin_amdgcn_mfma_f32_16x16x32_bf16(a, b, oc[jj], 0, 0, 0);
        }
      }
      #pragma unroll
      for (int jj = 0; jj < 2; ++jj){
        int d = (nc0 + jj) * 16 + ln;
        #pragma unroll
        for (int r = 0; r < 4; ++r){
          int t = mc * 16 + g * 4 + r;
          int byte = t * 128 + swz(t, d * 2);
          *reinterpret_cast<u16*>(reinterpret_cast<char*>(lds_q) + byte) = f2bf(oc[jj][r]);
        }
      }
    }
    __syncthreads();

    #pragma unroll
    for (int ks = 0; ks < 2; ++ks){
      short8 a[4];
      #pragma unroll
      for (int m = 0; m < 4; ++m){
        int row = m * 16 + ln;
        a[m] = *reinterpret_cast<const short8*>(
            reinterpret_cast<const char*>(lds_q) + row * 128 + swz(row, (ks * 32 + g * 8) * 2));
      }
      #pragma unroll
      for (int nt = 0; nt < 4; ++nt){
        int e = w * 64 + nt * 16 + ln;
        short8 b = *reinterpret_cast<const short8*>(
            wprojt + (long)e * 512 + h * 64 + ks * 32 + g * 8);
        #pragma unroll
        for (int m = 0; m < 4; ++m)
          oacc[m][nt] = __builtin_amdgcn_mfma_f32_16x16x32_bf16(a[m], b, oacc[m][nt], 0, 0, 0);
      }
    }
    __syncthreads();
  }

  #pragma unroll
  for (int nt = 0; nt < 4; ++nt){
    int col = w * 64 + nt * 16 + ln;
    float bias = bproj[col];
    #pragma unroll
    for (int m = 0; m < 4; ++m){
      #pragma unroll
      for (int r = 0; r < 4; ++r){
        int t = m * 16 + g * 4 + r;
        out[(tokbase + t) * 512 + col] = oacc[m][nt][r] + bias;
      }
    }
  }
}

extern "C" void kernel_launch(void* const* d_in, const int* in_sizes, int n_in,
                              void* d_out, int out_size, void* d_ws, size_t ws_size,
                              hipStream_t stream) {
  const float* x     = (const float*)d_in[0];
  const float* wqkv  = (const float*)d_in[1];
  const float* bqkv  = (const float*)d_in[2];
  const float* wproj = (const float*)d_in[3];
  const float* bproj = (const float*)d_in[4];
  float* out = (float*)d_out;

  // wq_swz 1.5M + wpt 0.5M + xbf 128M + qkv 384M = 514 MiB
  const size_t NEED = 538968064ULL;
  if (ws_size >= NEED){
    u16* wq_swz = (u16*)d_ws;
    u16* wpt    = (u16*)((char*)d_ws + 1572864);
    u16* xbf    = (u16*)((char*)d_ws + 2097152);
    u16* qkv    = (u16*)((char*)d_ws + 136314880);
    convert_weights_swz<<<512, 256, 0, stream>>>(wqkv, wproj, wq_swz, wpt);
    convert_x<<<32768, 256, 0, stream>>>(x, xbf);
    qkv_gemm<<<12288, 256, 0, stream>>>(xbf, wq_swz, bqkv, qkv);
    winattn_proj<<<2048, 512, 0, stream>>>(qkv, wpt, bproj, out);
  } else {
    u16* wqkvt  = (u16*)d_ws;
    u16* wprojt = wqkvt + 1536 * 512;
    convert_weights<<<512, 256, 0, stream>>>(wqkv, wproj, wqkvt, wprojt);
    fused_winattn<<<2048, 512, 0, stream>>>(x, wqkvt, bqkv, wprojt, bproj, out);
  }
}

// Round 4
// 662.608 us; speedup vs baseline: 2.6373x; 1.0357x over previous
//
#include <hip/hip_runtime.h>

typedef __attribute__((ext_vector_type(8))) short short8;
typedef __attribute__((ext_vector_type(4))) float f32x4;
typedef unsigned short u16;
typedef unsigned int u32;

// round-to-nearest-even f32 -> bf16
__device__ __forceinline__ u16 f2bf(float f){
  union { float f; u32 u; } v; v.f = f;
  u32 u = v.u;
  u32 r = (u + 0x7FFFu + ((u >> 16) & 1u)) >> 16;
  return (u16)r;
}

// pack two f32 -> bf16x2 (RNE), S0 in low half
__device__ __forceinline__ u32 cvtpk(float a, float b){
  u32 r;
  asm("v_cvt_pk_bf16_f32 %0, %1, %2" : "=v"(r) : "v"(a), "v"(b));
  return r;
}

// XOR swizzle on byte-in-row (bits 4..6) to break power-of-2 row strides
__device__ __forceinline__ int swz(int row, int cb){ return cb ^ ((row & 7) << 4); }

// async global->LDS 16B copy (wave-uniform LDS base, lane-strided dest)
__device__ __forceinline__ void gload16(const void* g, void* l){
  __builtin_amdgcn_global_load_lds(
      (const __attribute__((address_space(1))) unsigned int*)g,
      (__attribute__((address_space(3))) unsigned int*)l, 16, 0, 0);
}

// ===========================================================================
// K0: weights.  wq_swz = wqkv^T in pre-swizzled 128x64 bf16 tiles (for
// global_load_lds staging); wpt = plain transposed wproj (wpt[c][f]).
// ===========================================================================
__global__ void convert_weights_swz(const float* __restrict__ wqkv,
                                    const float* __restrict__ wproj,
                                    u16* __restrict__ wq_swz,
                                    u16* __restrict__ wpt){
  int c = blockIdx.x * 256 + threadIdx.x;
  union { u16 u[8]; uint4 v; } t;
  if (c < 98304){
    int tile = c >> 10, row = (c >> 3) & 127, c7 = c & 7;
    int bn = tile >> 3, kt = tile & 7;
    int j  = c7 ^ (row & 7);
    int e  = bn * 128 + row;
    int k0 = kt * 64 + j * 8;
    #pragma unroll
    for (int i = 0; i < 8; ++i) t.u[i] = f2bf(wqkv[(long)(k0 + i) * 1536 + e]);
    *reinterpret_cast<uint4*>(wq_swz + (long)c * 8) = t.v;
  } else {
    int t2 = c - 98304;
    int cc = t2 >> 6;
    int kc = (t2 & 63) << 3;
    #pragma unroll
    for (int i = 0; i < 8; ++i) t.u[i] = f2bf(wproj[(long)(kc + i) * 512 + cc]);
    *reinterpret_cast<uint4*>(wpt + (long)cc * 512 + kc) = t.v;
  }
}

// ===========================================================================
// K0b: x f32 -> bf16 pre-swizzled 128x64 tiles.
// ===========================================================================
__global__ void convert_x(const float* __restrict__ x, u16* __restrict__ xbf){
  int c = blockIdx.x * 256 + threadIdx.x;
  int tile = c >> 10, row = (c >> 3) & 127, c7 = c & 7;
  int bm = tile >> 3, kt = tile & 7;
  int j  = c7 ^ (row & 7);
  const float* src = x + (long)(bm * 128 + row) * 512 + kt * 64 + j * 8;
  float4 v0 = *reinterpret_cast<const float4*>(src);
  float4 v1 = *reinterpret_cast<const float4*>(src + 4);
  union { u16 u[8]; uint4 v; } t;
  t.u[0] = f2bf(v0.x); t.u[1] = f2bf(v0.y); t.u[2] = f2bf(v0.z); t.u[3] = f2bf(v0.w);
  t.u[4] = f2bf(v1.x); t.u[5] = f2bf(v1.y); t.u[6] = f2bf(v1.z); t.u[7] = f2bf(v1.w);
  *reinterpret_cast<uint4*>(xbf + (long)c * 8) = t.v;
}

// ===========================================================================
// K1: QKV GEMM (unchanged from round 3; ~600 TF, conflict-free)
// ===========================================================================
__global__ __launch_bounds__(256) void qkv_gemm(
    const u16*  __restrict__ xbf,
    const u16*  __restrict__ wswz,
    const float* __restrict__ bqkv,
    u16* __restrict__ qkv)
{
  __shared__ char smem[34816];
  char* ldsA = smem;
  char* ldsB = smem + 16384;
  u16*  ldsC = (u16*)smem;

  int hb   = blockIdx.x;
  int work = (hb & 7) * 1536 + (hb >> 3);
  int bn   = work % 12;
  int bm   = work / 12;

  const int tid = threadIdx.x;
  const int l = tid & 63, w = tid >> 6;
  const int g = l >> 4,  ln = l & 15;
  const int wm = w >> 1, wn = w & 1;

  f32x4 acc[4][4];
  #pragma unroll
  for (int m = 0; m < 4; ++m)
    #pragma unroll
    for (int n = 0; n < 4; ++n) acc[m][n] = (f32x4){0.f,0.f,0.f,0.f};

  const char* abase = (const char*)(xbf  + (long)(bm * 8) * 8192);
  const char* bbase = (const char*)(wswz + (long)(bn * 8) * 8192);

  for (int kt = 0; kt < 8; ++kt){
    __syncthreads();
    #pragma unroll
    for (int i = 0; i < 4; ++i){
      gload16(abase + (long)kt*16384 + (i*256 + tid)*16, ldsA + (i*256 + w*64)*16);
      gload16(bbase + (long)kt*16384 + (i*256 + tid)*16, ldsB + (i*256 + w*64)*16);
    }
    __syncthreads();
    #pragma unroll
    for (int ks = 0; ks < 2; ++ks){
      short8 a[4], b[4];
      #pragma unroll
      for (int m = 0; m < 4; ++m){
        int row = wm*64 + m*16 + ln;
        a[m] = *reinterpret_cast<const short8*>(ldsA + row*128 + (((ks*4 + g) ^ (row & 7)) << 4));
      }
      #pragma unroll
      for (int n = 0; n < 4; ++n){
        int row = wn*64 + n*16 + ln;
        b[n] = *reinterpret_cast<const short8*>(ldsB + row*128 + (((ks*4 + g) ^ (row & 7)) << 4));
      }
      #pragma unroll
      for (int m = 0; m < 4; ++m)
        #pragma unroll
        for (int n = 0; n < 4; ++n)
          acc[m][n] = __builtin_amdgcn_mfma_f32_16x16x32_bf16(a[m], b[n], acc[m][n], 0, 0, 0);
    }
  }

  __syncthreads();
  #pragma unroll
  for (int n = 0; n < 4; ++n){
    int col  = wn*64 + n*16 + ln;
    float bias = bqkv[bn*128 + col];
    #pragma unroll
    for (int m = 0; m < 4; ++m){
      int r0 = wm*64 + m*16 + g*4;
      #pragma unroll
      for (int r = 0; r < 4; ++r)
        ldsC[(r0 + r) * 136 + col] = f2bf(acc[m][n][r] + bias);
    }
  }
  __syncthreads();
  {
    int row = tid >> 1, half = tid & 1;
    const char* src = (const char*)(ldsC + row * 136 + half * 64);
    char* dst = (char*)qkv + ((long)(bm*128 + row) * 1536 + bn*128 + half*64) * 2;
    #pragma unroll
    for (int j = 0; j < 8; ++j)
      *reinterpret_cast<uint4*>(dst + j*16) = *reinterpret_cast<const uint4*>(src + j*16);
  }
}

// ===========================================================================
// K2 v2: fused window attention + projection, 64 KB LDS (2 blocks/CU).
// Wave w = head w. Swapped QK^T (S^T = mfma(K,Q)) -> softmax via 2 shfl_xor;
// P never touches LDS (cvt_pk + shfl redistribution into PV A-frags);
// O overwrites the V^T slot (all V reads precede by data dependence).
// Then one barrier; per-wave 64-col slice of out = O @ wproj + bias.
// ===========================================================================
__global__ __launch_bounds__(512, 4) void winattn_proj(
    const u16* __restrict__ qkv,
    const u16* __restrict__ wpt,
    const float* __restrict__ bproj,
    float* __restrict__ out)
{
  __shared__ u16 lds[8][4096];   // per wave: V^T then O (swizzled, 128B rows)
  const int tid = threadIdx.x;
  const int l = tid & 63, w = tid >> 6;
  const int g = l >> 4,  ln = l & 15;
  const int gh = g >> 1, gl = g & 1;
  const long tokb = (long)blockIdx.x * 64;
  u16* vt = lds[w];
  const int h = w;

  // ---- V rows -> swizzled V^T in LDS (wave-private) ----
  {
    const int dg = l & 3, tg = l >> 2;
    uint4 vr[4][2];
    #pragma unroll
    for (int r = 0; r < 4; ++r){
      const char* vrow = (const char*)(qkv + (tokb + tg*4 + r) * 1536 + 1024 + h*64 + dg*16);
      vr[r][0] = *reinterpret_cast<const uint4*>(vrow);
      vr[r][1] = *reinterpret_cast<const uint4*>(vrow + 16);
    }
    #pragma unroll
    for (int dd = 0; dd < 16; ++dd){
      int d = dg*16 + dd;
      int sub = dd & 7, hi = dd >> 3;
      uint2 pk;
      pk.x = (u32)((const u16*)&vr[0][hi])[sub] | ((u32)((const u16*)&vr[1][hi])[sub] << 16);
      pk.y = (u32)((const u16*)&vr[2][hi])[sub] | ((u32)((const u16*)&vr[3][hi])[sub] << 16);
      *reinterpret_cast<uint2*>((char*)vt + d*128 + swz(d, tg*8)) = pk;
    }
  }

  f32x4 oacc[4][4];
  #pragma unroll
  for (int m = 0; m < 4; ++m)
    #pragma unroll
    for (int n = 0; n < 4; ++n) oacc[m][n] = (f32x4){0.f,0.f,0.f,0.f};

  const int lnA = ln + 32*gl;    // shfl source lane (its pair is lnA+16)

  #pragma unroll
  for (int half = 0; half < 2; ++half){
    // ---- Q frags for this nq pair (B-operand of S^T) ----
    short8 qa[2][2];
    #pragma unroll
    for (int j = 0; j < 2; ++j){
      const char* qrow = (const char*)(qkv + (tokb + (half*2+j)*16 + ln) * 1536 + h*64 + g*8);
      qa[j][0] = *reinterpret_cast<const short8*>(qrow);
      qa[j][1] = *reinterpret_cast<const short8*>(qrow + 64);
    }
    // ---- S^T = mfma(K, Q): st[mk][j], lane holds col q=(half*2+j)*16+ln ----
    f32x4 st[4][2];
    #pragma unroll
    for (int mk = 0; mk < 4; ++mk){
      st[mk][0] = (f32x4){0.f,0.f,0.f,0.f};
      st[mk][1] = (f32x4){0.f,0.f,0.f,0.f};
    }
    #pragma unroll
    for (int mk = 0; mk < 4; ++mk){
      const char* krow = (const char*)(qkv + (tokb + mk*16 + ln) * 1536 + 512 + h*64 + g*8);
      short8 kb0 = *reinterpret_cast<const short8*>(krow);
      short8 kb1 = *reinterpret_cast<const short8*>(krow + 64);
      #pragma unroll
      for (int j = 0; j < 2; ++j){
        st[mk][j] = __builtin_amdgcn_mfma_f32_16x16x32_bf16(kb0, qa[j][0], st[mk][j], 0, 0, 0);
        st[mk][j] = __builtin_amdgcn_mfma_f32_16x16x32_bf16(kb1, qa[j][1], st[mk][j], 0, 0, 0);
      }
    }
    // ---- softmax over k (rows of S^T) for q = (half*2+j)*16+ln ----
    u32 warr[4][2][2];    // [mk][j][pair]  packed bf16 P
    #pragma unroll
    for (int j = 0; j < 2; ++j){
      float mx = -3.4e38f;
      #pragma unroll
      for (int mk = 0; mk < 4; ++mk)
        #pragma unroll
        for (int r = 0; r < 4; ++r) mx = fmaxf(mx, st[mk][j][r]);
      mx = fmaxf(mx, __shfl_xor(mx, 16, 64));
      mx = fmaxf(mx, __shfl_xor(mx, 32, 64));
      float s = 0.f;
      #pragma unroll
      for (int mk = 0; mk < 4; ++mk)
        #pragma unroll
        for (int r = 0; r < 4; ++r){
          float p = __expf((st[mk][j][r] - mx) * 0.125f);
          st[mk][j][r] = p; s += p;
        }
      s += __shfl_xor(s, 16, 64);
      s += __shfl_xor(s, 32, 64);
      float inv = 1.f / s;
      #pragma unroll
      for (int mk = 0; mk < 4; ++mk){
        warr[mk][j][0] = cvtpk(st[mk][j][0]*inv, st[mk][j][1]*inv);
        warr[mk][j][1] = cvtpk(st[mk][j][2]*inv, st[mk][j][3]*inv);
      }
    }
    // ---- partial PV for m-tiles {half*2, half*2+1} ----
    __builtin_amdgcn_s_setprio(1);
    #pragma unroll
    for (int ks = 0; ks < 2; ++ks){
      short8 vb[4];
      #pragma unroll
      for (int n = 0; n < 4; ++n){
        int row = n*16 + ln;
        vb[n] = *reinterpret_cast<const short8*>((char*)vt + row*128 + swz(row, (ks*32 + g*8)*2));
      }
      #pragma unroll
      for (int mo = 0; mo < 2; ++mo){
        int m = half*2 + mo;
        // a-frag: p[q=m*16+(l&15)][k=ks*32+g*8+s]; sources lanes lnA, lnA+16
        u32 c0a = warr[2*ks  ][mo][0], c0b = warr[2*ks  ][mo][1];
        u32 c1a = warr[2*ks+1][mo][0], c1b = warr[2*ks+1][mo][1];
        u32 s0a = (u32)__shfl((int)c0a, lnA, 64);
        u32 s1a = (u32)__shfl((int)c1a, lnA, 64);
        u32 s0b = (u32)__shfl((int)c0b, lnA, 64);
        u32 s1b = (u32)__shfl((int)c1b, lnA, 64);
        u32 t0a = (u32)__shfl((int)c0a, lnA+16, 64);
        u32 t1a = (u32)__shfl((int)c1a, lnA+16, 64);
        u32 t0b = (u32)__shfl((int)c0b, lnA+16, 64);
        u32 t1b = (u32)__shfl((int)c1b, lnA+16, 64);
        union { u32 u[4]; short8 v; } pf;
        pf.u[0] = gh ? s1a : s0a;
        pf.u[1] = gh ? s1b : s0b;
        pf.u[2] = gh ? t1a : t0a;
        pf.u[3] = gh ? t1b : t0b;
        #pragma unroll
        for (int n = 0; n < 4; ++n)
          oacc[m][n] = __builtin_amdgcn_mfma_f32_16x16x32_bf16(pf.v, vb[n], oacc[m][n], 0, 0, 0);
      }
    }
    __builtin_amdgcn_s_setprio(0);
  }

  // ---- O -> vt slot (V dead: all vt reads precede via MFMA data dep) ----
  #pragma unroll
  for (int m = 0; m < 4; ++m)
    #pragma unroll
    for (int n = 0; n < 4; ++n){
      int d = n*16 + ln;
      #pragma unroll
      for (int r = 0; r < 4; ++r){
        int t = m*16 + g*4 + r;
        *reinterpret_cast<u16*>((char*)vt + t*128 + swz(t, d*2)) = f2bf(oacc[m][n][r]);
      }
    }

  __syncthreads();

  // ---- proj: acc(64 tok x cols w*64..w*64+64) += O_hh @ wproj_hh ----
  f32x4 acc[4][4];
  #pragma unroll
  for (int m = 0; m < 4; ++m)
    #pragma unroll
    for (int n = 0; n < 4; ++n) acc[m][n] = (f32x4){0.f,0.f,0.f,0.f};

  for (int hh = 0; hh < 8; ++hh){
    const char* obuf = (const char*)lds[hh];
    #pragma unroll
    for (int ks = 0; ks < 2; ++ks){
      short8 a[4], b[4];
      #pragma unroll
      for (int m = 0; m < 4; ++m){
        int row = m*16 + ln;
        a[m] = *reinterpret_cast<const short8*>(obuf + row*128 + swz(row, (ks*32 + g*8)*2));
      }
      #pragma unroll
      for (int n = 0; n < 4; ++n){
        int e = w*64 + n*16 + ln;
        b[n] = *reinterpret_cast<const short8*>(wpt + (long)e*512 + hh*64 + ks*32 + g*8);
      }
      __builtin_amdgcn_s_setprio(1);
      #pragma unroll
      for (int m = 0; m < 4; ++m)
        #pragma unroll
        for (int n = 0; n < 4; ++n)
          acc[m][n] = __builtin_amdgcn_mfma_f32_16x16x32_bf16(a[m], b[n], acc[m][n], 0, 0, 0);
      __builtin_amdgcn_s_setprio(0);
    }
  }

  // ---- epilogue: bias + f32 stores ----
  #pragma unroll
  for (int n = 0; n < 4; ++n){
    int col = w*64 + n*16 + ln;
    float bias = bproj[col];
    #pragma unroll
    for (int m = 0; m < 4; ++m){
      #pragma unroll
      for (int r = 0; r < 4; ++r){
        int t = m*16 + g*4 + r;
        out[(tokb + t) * 512 + col] = acc[m][n][r] + bias;
      }
    }
  }
}

// ===========================================================================
// Fallback (round-1 fused kernel) for small ws_size
// ===========================================================================
__global__ void convert_weights(const float* __restrict__ wqkv,
                                const float* __restrict__ wproj,
                                u16* __restrict__ wqkvt,
                                u16* __restrict__ wprojt){
  int tid = blockIdx.x * 256 + threadIdx.x;
  union { u16 u[8]; uint4 v; } tmp;
  if (tid < 1536 * 64){
    int e  = tid >> 6;
    int kc = (tid & 63) << 3;
    #pragma unroll
    for (int i = 0; i < 8; ++i) tmp.u[i] = f2bf(wqkv[(long)(kc + i) * 1536 + e]);
    *reinterpret_cast<uint4*>(wqkvt + (long)e * 512 + kc) = tmp.v;
  } else {
    int t2 = tid - 1536 * 64;
    int c  = t2 >> 6;
    int kc = (t2 & 63) << 3;
    #pragma unroll
    for (int i = 0; i < 8; ++i) tmp.u[i] = f2bf(wproj[(long)(kc + i) * 512 + c]);
    *reinterpret_cast<uint4*>(wprojt + (long)c * 512 + kc) = tmp.v;
  }
}

__global__ __launch_bounds__(512, 2) void fused_winattn(
    const float* __restrict__ x,
    const u16*  __restrict__ wqkvt,
    const float* __restrict__ bqkv,
    const u16*  __restrict__ wprojt,
    const float* __restrict__ bproj,
    float* __restrict__ out)
{
  __shared__ u16 lds_x[64 * 512];
  __shared__ u16 lds_q[64 * 64];
  __shared__ u16 lds_k[64 * 64];
  __shared__ u16 lds_vt[64 * 64];
  __shared__ u16 lds_p[64 * 64];

  const int tid = threadIdx.x;
  const int l   = tid & 63;
  const int w   = tid >> 6;
  const int g   = l >> 4;
  const int ln  = l & 15;
  const long tokbase = (long)blockIdx.x * 64;

  {
    const float4* xv = reinterpret_cast<const float4*>(x + tokbase * 512);
    #pragma unroll
    for (int j = 0; j < 16; ++j){
      int i   = j * 512 + tid;
      int row = i >> 7;
      int c4  = i & 127;
      float4 v = xv[i];
      uint2 pk;
      pk.x = (u32)f2bf(v.x) | ((u32)f2bf(v.y) << 16);
      pk.y = (u32)f2bf(v.z) | ((u32)f2bf(v.w) << 16);
      int byte = row * 1024 + swz(row, c4 * 8);
      *reinterpret_cast<uint2*>(reinterpret_cast<char*>(lds_x) + byte) = pk;
    }
  }

  f32x4 oacc[4][4];
  #pragma unroll
  for (int m = 0; m < 4; ++m)
    #pragma unroll
    for (int n = 0; n < 4; ++n) oacc[m][n] = (f32x4){0.f, 0.f, 0.f, 0.f};

  const int mw   = w & 3;
  const int half = w >> 2;

  __syncthreads();

  for (int h = 0; h < 8; ++h){
    f32x4 qacc[6];
    #pragma unroll
    for (int j = 0; j < 6; ++j) qacc[j] = (f32x4){0.f, 0.f, 0.f, 0.f};
    int ebase[6];
    #pragma unroll
    for (int j = 0; j < 6; ++j){
      int nt = half * 6 + j;
      int sec = nt >> 2;
      ebase[j] = sec * 512 + h * 64 + (nt & 3) * 16;
    }
    const int arow = mw * 16 + ln;
    #pragma unroll
    for (int ks = 0; ks < 16; ++ks){
      short8 a = *reinterpret_cast<const short8*>(
          reinterpret_cast<const char*>(lds_x) + arow * 1024 + swz(arow, (ks * 32 + g * 8) * 2));
      #pragma unroll
      for (int j = 0; j < 6; ++j){
        short8 b = *reinterpret_cast<const short8*>(
            wqkvt + (long)(ebase[j] + ln) * 512 + ks * 32 + g * 8);
        qacc[j] = __builtin_amdgcn_mfma_f32_16x16x32_bf16(a, b, qacc[j], 0, 0, 0);
      }
    }
    #pragma unroll
    for (int j = 0; j < 6; ++j){
      int nt  = half * 6 + j;
      int sec = nt >> 2;
      float bias = bqkv[ebase[j] + ln];
      if (sec < 2){
        u16* dst = (sec == 0) ? lds_q : lds_k;
        int c = (nt & 3) * 16 + ln;
        #pragma unroll
        for (int r = 0; r < 4; ++r){
          int t = mw * 16 + g * 4 + r;
          int byte = t * 128 + swz(t, c * 2);
          *reinterpret_cast<u16*>(reinterpret_cast<char*>(dst) + byte) = f2bf(qacc[j][r] + bias);
        }
      } else {
        int d  = (nt & 3) * 16 + ln;
        int t0 = mw * 16 + g * 4;
        uint2 pk;
        pk.x = (u32)f2bf(qacc[j][0] + bias) | ((u32)f2bf(qacc[j][1] + bias) << 16);
        pk.y = (u32)f2bf(qacc[j][2] + bias) | ((u32)f2bf(qacc[j][3] + bias) << 16);
        int byte = d * 128 + swz(d, t0 * 2);
        *reinterpret_cast<uint2*>(reinterpret_cast<char*>(lds_vt) + byte) = pk;
      }
    }
    __syncthreads();

    if (w < 4){
      f32x4 sacc[4];
      #pragma unroll
      for (int jt = 0; jt < 4; ++jt) sacc[jt] = (f32x4){0.f, 0.f, 0.f, 0.f};
      #pragma unroll
      for (int ks = 0; ks < 2; ++ks){
        int qrow = w * 16 + ln;
        short8 a = *reinterpret_cast<const short8*>(
            reinterpret_cast<const char*>(lds_q) + qrow * 128 + swz(qrow, (ks * 32 + g * 8) * 2));
        #pragma unroll
        for (int jt = 0; jt < 4; ++jt){
          int krow = jt * 16 + ln;
          short8 b = *reinterpret_cast<const short8*>(
              reinterpret_cast<const char*>(lds_k) + krow * 128 + swz(krow, (ks * 32 + g * 8) * 2));
          sacc[jt] = __builtin_amdgcn_mfma_f32_16x16x32_bf16(a, b, sacc[jt], 0, 0, 0);
        }
      }
      #pragma unroll
      for (int r = 0; r < 4; ++r){
        float mx = fmaxf(fmaxf(sacc[0][r], sacc[1][r]), fmaxf(sacc[2][r], sacc[3][r]));
        mx = fmaxf(mx, __shfl_xor(mx, 1, 64));
        mx = fmaxf(mx, __shfl_xor(mx, 2, 64));
        mx = fmaxf(mx, __shfl_xor(mx, 4, 64));
        mx = fmaxf(mx, __shfl_xor(mx, 8, 64));
        float p[4], s = 0.f;
        #pragma unroll
        for (int jt = 0; jt < 4; ++jt){
          p[jt] = __expf((sacc[jt][r] - mx) * 0.125f);
          s += p[jt];
        }
        s += __shfl_xor(s, 1, 64);
        s += __shfl_xor(s, 2, 64);
        s += __shfl_xor(s, 4, 64);
        s += __shfl_xor(s, 8, 64);
        float inv = 1.f / s;
        int i = w * 16 + g * 4 + r;
        #pragma unroll
        for (int jt = 0; jt < 4; ++jt){
          int c = jt * 16 + ln;
          int byte = i * 128 + swz(i, c * 2);
          *reinterpret_cast<u16*>(reinterpret_cast<char*>(lds_p) + byte) = f2bf(p[jt] * inv);
        }
      }
    }
    __syncthreads();

    {
      int mc  = w & 3;
      int nc0 = (w >> 2) * 2;
      f32x4 oc[2];
      oc[0] = (f32x4){0.f, 0.f, 0.f, 0.f};
      oc[1] = (f32x4){0.f, 0.f, 0.f, 0.f};
      #pragma unroll
      for (int ks = 0; ks < 2; ++ks){
        int prow = mc * 16 + ln;
        short8 a = *reinterpret_cast<const short8*>(
            reinterpret_cast<const char*>(lds_p) + prow * 128 + swz(prow, (ks * 32 + g * 8) * 2));
        #pragma unroll
        for (int jj = 0; jj < 2; ++jj){
          int vrow = (nc0 + jj) * 16 + ln;
          short8 b = *reinterpret_cast<const short8*>(
              reinterpret_cast<const char*>(lds_vt) + vrow * 128 + swz(vrow, (ks * 32 + g * 8) * 2));
          oc[jj] = __builtin_amdgcn_mfma_f32_16x16x32_bf16(a, b, oc[jj], 0, 0, 0);
        }
      }
      #pragma unroll
      for (int jj = 0; jj < 2; ++jj){
        int d = (nc0 + jj) * 16 + ln;
        #pragma unroll
        for (int r = 0; r < 4; ++r){
          int t = mc * 16 + g * 4 + r;
          int byte = t * 128 + swz(t, d * 2);
          *reinterpret_cast<u16*>(reinterpret_cast<char*>(lds_q) + byte) = f2bf(oc[jj][r]);
        }
      }
    }
    __syncthreads();

    #pragma unroll
    for (int ks = 0; ks < 2; ++ks){
      short8 a[4];
      #pragma unroll
      for (int m = 0; m < 4; ++m){
        int row = m * 16 + ln;
        a[m] = *reinterpret_cast<const short8*>(
            reinterpret_cast<const char*>(lds_q) + row * 128 + swz(row, (ks * 32 + g * 8) * 2));
      }
      #pragma unroll
      for (int nt = 0; nt < 4; ++nt){
        int e = w * 64 + nt * 16 + ln;
        short8 b = *reinterpret_cast<const short8*>(
            wprojt + (long)e * 512 + h * 64 + ks * 32 + g * 8);
        #pragma unroll
        for (int m = 0; m < 4; ++m)
          oacc[m][nt] = __builtin_amdgcn_mfma_f32_16x16x32_bf16(a[m], b, oacc[m][nt], 0, 0, 0);
      }
    }
    __syncthreads();
  }

  #pragma unroll
  for (int nt = 0; nt < 4; ++nt){
    int col = w * 64 + nt * 16 + ln;
    float bias = bproj[col];
    #pragma unroll
    for (int m = 0; m < 4; ++m){
      #pragma unroll
      for (int r = 0; r < 4; ++r){
        int t = m * 16 + g * 4 + r;
        out[(tokbase + t) * 512 + col] = oacc[m][nt][r] + bias;
      }
    }
  }
}

extern "C" void kernel_launch(void* const* d_in, const int* in_sizes, int n_in,
                              void* d_out, int out_size, void* d_ws, size_t ws_size,
                              hipStream_t stream) {
  const float* x     = (const float*)d_in[0];
  const float* wqkv  = (const float*)d_in[1];
  const float* bqkv  = (const float*)d_in[2];
  const float* wproj = (const float*)d_in[3];
  const float* bproj = (const float*)d_in[4];
  float* out = (float*)d_out;

  // wq_swz 1.5M + wpt 0.5M + xbf 128M + qkv 384M = 514 MiB
  const size_t NEED = 538968064ULL;
  if (ws_size >= NEED){
    u16* wq_swz = (u16*)d_ws;
    u16* wpt    = (u16*)((char*)d_ws + 1572864);
    u16* xbf    = (u16*)((char*)d_ws + 2097152);
    u16* qkv    = (u16*)((char*)d_ws + 136314880);
    convert_weights_swz<<<512, 256, 0, stream>>>(wqkv, wproj, wq_swz, wpt);
    convert_x<<<32768, 256, 0, stream>>>(x, xbf);
    qkv_gemm<<<12288, 256, 0, stream>>>(xbf, wq_swz, bqkv, qkv);
    winattn_proj<<<2048, 512, 0, stream>>>(qkv, wpt, bproj, out);
  } else {
    u16* wqkvt  = (u16*)d_ws;
    u16* wprojt = wqkvt + 1536 * 512;
    convert_weights<<<512, 256, 0, stream>>>(wqkv, wproj, wqkvt, wprojt);
    fused_winattn<<<2048, 512, 0, stream>>>(x, wqkvt, bqkv, wprojt, bproj, out);
  }
}